// Round 1
// 79.903 us; speedup vs baseline: 1.0975x; 1.0975x over previous
//
#include <hip/hip_runtime.h>
#include <hip/hip_bf16.h>
#include <math.h>

// Problem constants
#define NB 256
#define LL 200
#define DD 64
#define ITEMS_N 10000
#define RANK 16
#define ALPHA 1.0001f
#define INV_ALPHA (1.0f/1.0001f)
#define INV_SQRT_HEAD 0.17677669529663687f  // 1/sqrt(32)

typedef __attribute__((ext_vector_type(8))) short short8v;
typedef __attribute__((ext_vector_type(4))) float f32x4;

static __device__ __forceinline__ unsigned short f2b(float f) {
    unsigned u = __float_as_uint(f);
    unsigned r = (u + 0x7fffu + ((u >> 16) & 1u)) >> 16;   // RNE
    return (unsigned short)r;
}
static __device__ __forceinline__ float b2f(unsigned short h) {
    return __uint_as_float(((unsigned)h) << 16);
}

// LDS layout (bytes) for mega
#define OFF_A     0        // Abuf u16[208][72] : S2 (MFMA output), later Vt u16[64][232]
#define OFF_TB    29952    // Tb u16[208][232]
// scratch aliased in the head of Tb (all dead before Lk tiles touch them:
// rows>=48 never overlap; rows<48 written only after 1d):
#define OFF_CL32  (OFF_TB + 0)       // f32[32][33] candidate Gram   (4224 B)
#define OFF_U32   (OFF_TB + 4224)    // f32[32][17] selection chol   (2176 B)
#define OFF_CLG   (OFF_TB + 6400)    // f32[200][17] pivot columns  (13600 B, ends 20000)
#define OFF_XB    (OFF_TB + 20000)   // u16[208][72] x bf16          (29952 B, ends 49952)
#define OFF_WQB   (OFF_TB + 49952)   // u16[64][72]  Wq bf16         ( 9216 B, ends 59168)
#define OFF_WVB   (OFF_TB + 59168)   // u16[64][72]  Wv bf16         ( 9216 B, ends 68384)
#define OFF_BQS   (OFF_TB + 68384)   // f32[64]
#define OFF_BVS   (OFF_TB + 68640)   // f32[64]  (scratch ends 68896 < 96512)
#define OFF_UL    126464   // Ul f32[200][16] -> later Wdb u16[64][72]
#define OFF_UB    139264   // Ub u16[208][16] (ends exactly at OFF_PB); phase 10:
                           //   per-wave halfbuf u16[16][36] x 16 = 18,432 B
                           //   (139264..157696 < dv at 159744)
// small chol scratch in Ub region (dead before Ub written in phase 4+5):
#define OFF_IDSL  (OFF_UB + 0)       // int[200]
#define OFF_PIV   (OFF_UB + 928)     // int[16]
#define OFF_INVSQ (OFF_UB + 992)     // f32[16]
#define OFF_IDP   (OFF_UB + 1056)    // int[16]
#define OFF_PB    145920   // Pb u16[208][16]; phases 2-4: Maug f32[16][33]
#define OFF_MAUG  (OFF_PB + 0)       // 2112 B inside dead Pb (Pb first written ph.7)
#define OFF_ZB    152576   // Zb u16[16][224]
#define OFF_DV    159744   // dv f32[208]
#define OFF_RED   160576   // red f32[32]
#define OFF_SCAL  160704   // scal f32[4]
#define OFF_ZPAD  160720   // 64 B zeros
#define LDS_TOTAL 160784

// ---------------------------------------------------------------------------
// K_mega (single kernel): qv(MFMA) + chol (overlapped with Lk MFMA) -> P(MFMA)
//   -> T(MFMA) -> W=T.*T^T + denom -> softmax -> PV(MFMA) -> proj(MFMA) -> LN.
// grid B, block 1024 (16 waves), dynamic LDS 160,784 B (1 block/CU).
// This round: 4-row-parallel softmax (16-lane groups, 4-step shuffles),
//   full-strip mask register prefetch, Vt async issue-early (T14),
//   early Gram-gather issue, float4-vectorized staging.
// ---------------------------------------------------------------------------
__global__ __launch_bounds__(1024) void mega_kernel(
        const float* __restrict__ x,    const float* __restrict__ mask,
        const int*   __restrict__ ids,  const float* __restrict__ C,
        const float* __restrict__ Wq,   const float* __restrict__ bq,
        const float* __restrict__ Wv,   const float* __restrict__ bv,
        const float* __restrict__ Wd,   const float* __restrict__ bd,
        const float* __restrict__ gamma,const float* __restrict__ beta,
        unsigned short* __restrict__ Vg, float* __restrict__ out) {
    extern __shared__ char smem[];
    unsigned short* Abuf = (unsigned short*)(smem + OFF_A);   // S2 then Vt
    unsigned short* Tb   = (unsigned short*)(smem + OFF_TB);
    float* Cl32  = (float*)(smem + OFF_CL32);
    float* U32l  = (float*)(smem + OFF_U32);
    float* Clg   = (float*)(smem + OFF_CLG);
    unsigned short* xbu  = (unsigned short*)(smem + OFF_XB);
    unsigned short* Wqbu = (unsigned short*)(smem + OFF_WQB);
    unsigned short* Wvbu = (unsigned short*)(smem + OFF_WVB);
    float* bqs   = (float*)(smem + OFF_BQS);
    float* bvs   = (float*)(smem + OFF_BVS);
    float*          Ul   = (float*)(smem + OFF_UL);
    unsigned short* Wdb  = (unsigned short*)(smem + OFF_UL);  // alias (Ul dead)
    unsigned short* Ub   = (unsigned short*)(smem + OFF_UB);
    unsigned short* Pb   = (unsigned short*)(smem + OFF_PB);
    unsigned short* Zb   = (unsigned short*)(smem + OFF_ZB);
    float* dv   = (float*)(smem + OFF_DV);
    float* red  = (float*)(smem + OFF_RED);
    float* scal = (float*)(smem + OFF_SCAL);
    const short8v* zpad = (const short8v*)(smem + OFF_ZPAD);
    int*   idsl  = (int*)(smem + OFF_IDSL);
    int*   pivots= (int*)(smem + OFF_PIV);
    float* invsqv= (float*)(smem + OFF_INVSQ);
    int*   idpv  = (int*)(smem + OFF_IDP);
    float* Maug  = (float*)(smem + OFF_MAUG);

    int t = threadIdx.x;
    int b = blockIdx.x;
    int wv_ = t >> 6, lane = t & 63, fr = lane & 15, g = lane >> 4;

    // ---- -1) early Gram-gather issue: ~1.8k cyc chained HBM latency hides
    //      under the whole phase-0 staging (ids read direct from global) ----
    int ga_ = t >> 5, gc_ = t & 31;
    float cgv;
    {
        int ia = ids[b*LL + ga_];
        int ic = ids[b*LL + gc_];
        cgv = C[(size_t)ia*ITEMS_N + ic];
    }

    // ---- 0) stage ids, x->bf16, Wq/Wv->bf16, biases; zero pads ----
    {
        float4 z4; z4.x = 0.f; z4.y = 0.f; z4.z = 0.f; z4.w = 0.f;
        // Tb rows 200-207 (3,712 B)
        float4* tz = (float4*)(smem + OFF_TB + 92800);
        for (int i = t; i < 232; i += 1024) tz[i] = z4;
        // Zb
        float4* zz = (float4*)Zb;
        for (int i = t; i < 448; i += 1024) zz[i] = z4;
        if (t < 4) ((float4*)(smem + OFF_ZPAD))[t] = z4;
        if (t < 64)  ((unsigned*)(smem + OFF_UB + 6400))[t] = 0;   // Ub rows 200-207
        // xb pad rows 200-207 (1,152 B)
        for (int i = t; i < 288; i += 1024) ((unsigned*)(smem + OFF_XB + 28800))[i] = 0;
        // x -> bf16 (float4-vectorized: 3.125 loads/thread, packed b64 writes)
        const float4* x4p = (const float4*)(x + (size_t)b*12800);
        #pragma unroll
        for (int it2 = 0; it2 < 4; ++it2) {
            int i4 = t + it2*1024;
            if (i4 < 3200) {
                float4 v4 = x4p[i4];
                int r = i4 >> 4, k4 = (i4 & 15) << 2;
                unsigned lo = (unsigned)f2b(v4.x) | ((unsigned)f2b(v4.y) << 16);
                unsigned hi = (unsigned)f2b(v4.z) | ((unsigned)f2b(v4.w) << 16);
                *(uint2*)(xbu + r*72 + k4) = make_uint2(lo, hi);
            }
        }
        // Wq/Wv -> bf16 (one float4 each per thread)
        {
            float4 q4 = ((const float4*)Wq)[t];
            float4 w4 = ((const float4*)Wv)[t];
            int d2 = t >> 4, k4 = (t & 15) << 2;
            unsigned qlo = (unsigned)f2b(q4.x) | ((unsigned)f2b(q4.y) << 16);
            unsigned qhi = (unsigned)f2b(q4.z) | ((unsigned)f2b(q4.w) << 16);
            *(uint2*)(Wqbu + d2*72 + k4) = make_uint2(qlo, qhi);
            unsigned vlo = (unsigned)f2b(w4.x) | ((unsigned)f2b(w4.y) << 16);
            unsigned vhi = (unsigned)f2b(w4.z) | ((unsigned)f2b(w4.w) << 16);
            *(uint2*)(Wvbu + d2*72 + k4) = make_uint2(vlo, vhi);
        }
        if (t < 64) { bqs[t] = bq[t]; bvs[t] = bv[t]; }
        if (t < LL) idsl[t] = ids[b*LL + t];
        Cl32[ga_*33 + gc_] = cgv;     // gather landed during staging
    }
    __syncthreads();

    // ---- 0.5) S2/V MFMA ----
    for (int tile = wv_; tile < 52; tile += 16) {
        int R = tile >> 2, Dt = tile & 3;
        const char* ar = (const char*)smem + OFF_XB + (R*16 + fr)*144;
        const char* qr = (const char*)smem + OFF_WQB + (Dt*16 + fr)*144;
        const char* vr = (const char*)smem + OFF_WVB + (Dt*16 + fr)*144;
        short8v a0 = *(const short8v*)(ar + g*16);
        short8v a1 = *(const short8v*)(ar + 64 + g*16);
        f32x4 qa = {0.f,0.f,0.f,0.f};
        f32x4 va = {0.f,0.f,0.f,0.f};
        qa = __builtin_amdgcn_mfma_f32_16x16x32_bf16(a0, *(const short8v*)(qr + g*16), qa, 0,0,0);
        qa = __builtin_amdgcn_mfma_f32_16x16x32_bf16(a1, *(const short8v*)(qr + 64 + g*16), qa, 0,0,0);
        va = __builtin_amdgcn_mfma_f32_16x16x32_bf16(a0, *(const short8v*)(vr + g*16), va, 0,0,0);
        va = __builtin_amdgcn_mfma_f32_16x16x32_bf16(a1, *(const short8v*)(vr + 64 + g*16), va, 0,0,0);
        int col = Dt*16 + fr;
        float bqc = bqs[col], bvc = bvs[col];
        #pragma unroll
        for (int reg = 0; reg < 4; ++reg) {
            int row = R*16 + g*4 + reg;
            float sv = qa[reg] + bqc;
            Abuf[row*72 + col] = (row < LL) ? f2b(sv*sv) : (unsigned short)0;
            if (row < LL) Vg[(size_t)b*12800 + row*64 + col] = f2b(va[reg] + bvc);
        }
    }
    __syncthreads();

    // ---- 1b) wave 0: selection Cholesky (registers + shuffles, 0 barriers);
    //      waves 1-15: Lk MFMA tiles R>=3 (Tb rows >=48, above all chol
    //      scratch; XB/WQB/WVB there are dead after phase 0.5). ----
    if (wv_ == 0) {
        int a = lane & 31;
        float diag = Cl32[a*33 + a] - 1.0f;
        float ur[16];
        int   mypiv = 0; float myinv = 0.f;
        bool  removed = false;
        #pragma unroll
        for (int s = 0; s < RANK; ++s) {
            float v = removed ? -3e38f : diag;
            int idx = a;
            #pragma unroll
            for (int off = 16; off > 0; off >>= 1) {
                float v2 = __shfl_xor(v, off);
                int   i2 = __shfl_xor(idx, off);
                if (v2 > v || (v2 == v && i2 < idx)) { v = v2; idx = i2; }
            }
            int p = idx; float dp = v;          // wave-uniform (p < 32)
            float iv = (dp < 1e-9f) ? 0.0f : (1.0f/sqrtf(dp));
            float c = Cl32[a*33 + p] - ((a == p) ? 1.0f : 0.0f);
            #pragma unroll
            for (int k = 0; k < s; ++k) {
                float upk = __shfl(ur[k], p);   // pivot row value U32[p][k]
                c -= ur[k] * upk;
            }
            float u = c * iv;
            ur[s] = u;
            diag -= u*u;
            if (a == p) removed = true;
            if (lane == s) { mypiv = p; myinv = iv; }
        }
        #pragma unroll
        for (int s = 0; s < RANK; ++s) U32l[a*17 + s] = ur[s];
        if (lane < 16) {
            pivots[lane] = mypiv;
            invsqv[lane] = myinv;
            idpv[lane]   = idsl[mypiv];
        }
    } else {
        for (int tile = 39 + (wv_ - 1); tile < 169; tile += 15) {
            int R = tile / 13, Cc = tile - R*13;
            short8v a0 = *(const short8v*)((char*)Abuf + (R*16 + fr)*144 + g*16);
            short8v a1 = *(const short8v*)((char*)Abuf + (R*16 + fr)*144 + 64 + g*16);
            short8v b0 = *(const short8v*)((char*)Abuf + (Cc*16 + fr)*144 + g*16);
            short8v b1 = *(const short8v*)((char*)Abuf + (Cc*16 + fr)*144 + 64 + g*16);
            f32x4 acc = {0.f, 0.f, 0.f, 0.f};
            acc = __builtin_amdgcn_mfma_f32_16x16x32_bf16(a0, b0, acc, 0, 0, 0);
            acc = __builtin_amdgcn_mfma_f32_16x16x32_bf16(a1, b1, acc, 0, 0, 0);
            int col = Cc*16 + fr;
            #pragma unroll
            for (int reg = 0; reg < 4; ++reg) {
                int row = R*16 + g*4 + reg;
                if (row < LL && col < LL) Tb[row*232 + col] = f2b(acc[reg]);
            }
        }
    }
    __syncthreads();

    // ---- 1c) gather the 16 pivot columns at all 200 rows (one round) ----
    for (int i = t; i < 3200; i += 1024) {
        int r = i >> 4, s = i & 15;
        Clg[r*17 + s] = C[(size_t)idsl[r]*ITEMS_N + idpv[s]];
    }
    __syncthreads();

    // ---- 1d) per-thread full U-row recursion (no barriers inside) ----
    if (t < LL) {
        float ur[16];
        #pragma unroll
        for (int s = 0; s < RANK; ++s) {
            int p = pivots[s];
            float c = Clg[t*17 + s] - ((t == p) ? 1.0f : 0.0f);
            #pragma unroll
            for (int k = 0; k < s; ++k) c -= ur[k] * U32l[p*17 + k];
            ur[s] = c * invsqv[s];
        }
        #pragma unroll
        for (int s = 0; s < RANK; ++s) Ul[t*RANK + s] = ur[s];
    }
    __syncthreads();

    // ---- Vt async prefetch (T14 issue-early/write-late: Vg complete since
    //      the 0.5 barrier; latency hides under phases 2-5; LDS write in 7) ----
    unsigned short vreg[13];
    {
        const unsigned short* vgp = Vg + (size_t)b*12800;
        #pragma unroll
        for (int it2 = 0; it2 < 13; ++it2) {
            int i = t + it2*1024;
            vreg[it2] = (i < 12800) ? vgp[i] : (unsigned short)0;
        }
    }

    // ---- 2) M = alpha I + U^T U (1024 threads: (r,c,q), 50 iters + shfl) ----
    {
        int r = t >> 6, c = (t >> 2) & 15, q = t & 3;
        float acc = 0.f;
        for (int i = q*50; i < q*50 + 50; ++i)
            acc = fmaf(Ul[i*RANK + r], Ul[i*RANK + c], acc);
        acc += __shfl_xor(acc, 1);
        acc += __shfl_xor(acc, 2);
        if (q == 0) {
            Maug[r*33 + c] = acc + ((r == c) ? ALPHA : 0.f);
            Maug[r*33 + 16 + c] = (r == c) ? 1.0f : 0.0f;
        }
    }
    __syncthreads();
    // ---- 3) Gauss-Jordan on wave 0; waves 1-15: Tb pad-col zero + the 39
    //      remaining Lk tiles R<3 (rows 0-47; chol scratch there dead). ----
    if (wv_ == 0) {
        for (int s = 0; s < 16; ++s) {
            float pvinv = 1.0f / Maug[s*33 + s];
            float rowv = 0.f;
            if (lane < 33) { rowv = Maug[s*33 + lane] * pvinv; Maug[s*33 + lane] = rowv; }
            for (int r = 0; r < 16; ++r) {
                if (r == s) continue;
                float f = Maug[r*33 + s];
                if (lane < 33) Maug[r*33 + lane] -= f * rowv;
            }
        }
    } else {
        // Tb pad cols 200-231 of rows 0-199 (chol scratch in Tb head is dead)
        for (int i = t - 64; i < 3200; i += 960) {
            int r = i >> 4, c2 = i & 15;
            *(unsigned*)(smem + OFF_TB + r*464 + 400 + c2*4) = 0;
        }
        for (int tile = wv_ - 1; tile < 39; tile += 15) {
            int R = tile / 13, Cc = tile - R*13;
            short8v a0 = *(const short8v*)((char*)Abuf + (R*16 + fr)*144 + g*16);
            short8v a1 = *(const short8v*)((char*)Abuf + (R*16 + fr)*144 + 64 + g*16);
            short8v b0 = *(const short8v*)((char*)Abuf + (Cc*16 + fr)*144 + g*16);
            short8v b1 = *(const short8v*)((char*)Abuf + (Cc*16 + fr)*144 + 64 + g*16);
            f32x4 acc = {0.f, 0.f, 0.f, 0.f};
            acc = __builtin_amdgcn_mfma_f32_16x16x32_bf16(a0, b0, acc, 0, 0, 0);
            acc = __builtin_amdgcn_mfma_f32_16x16x32_bf16(a1, b1, acc, 0, 0, 0);
            int col = Cc*16 + fr;
            #pragma unroll
            for (int reg = 0; reg < 4; ++reg) {
                int row = R*16 + g*4 + reg;
                if (row < LL && col < LL) Tb[row*232 + col] = f2b(acc[reg]);
            }
        }
    }
    __syncthreads();
    // ---- 4+5) Z = U*Minv -> Zb ; Ub = bf16(Ul). (Maug in dead Pb region,
    //      disjoint from Ub — no R10-style race.) ----
    for (int idx = t; idx < LL*RANK; idx += 1024) {
        int i = idx >> 4, r = idx & 15;
        float acc = 0.f;
        #pragma unroll
        for (int k = 0; k < 16; ++k) acc = fmaf(Ul[i*RANK + k], Maug[k*33 + 16 + r], acc);
        Zb[r*224 + i] = f2b(acc);
        Ub[idx] = f2b(Ul[idx]);
    }
    __syncthreads();            // Maug + Ul dead after this; Tb holds full Lk
    // ---- 7) Vt stage (from vreg; S2 dead) + Wdb stage (Ul dead) +
    //         P = Lk@Z MFMA -> Pb ----
    {
        unsigned short* Vt = Abuf;
        #pragma unroll
        for (int it2 = 0; it2 < 13; ++it2) {
            int i = t + it2*1024;
            if (i < 12800) Vt[(i & 63)*232 + (i >> 6)] = vreg[it2];
        }
        for (int i = t; i < 2048; i += 1024) {
            int d = i >> 5, mc = i & 31;
            Vt[d*232 + 200 + mc] = 0;
        }
        for (int i = t; i < 4096; i += 1024) {
            int dd = i >> 6, k = i & 63;
            Wdb[dd*72 + k] = f2b(Wd[i]);
        }
    }
    for (int strip = wv_; strip < 13; strip += 16) {
        f32x4 acc = {0.f, 0.f, 0.f, 0.f};
        const char* arow = (const char*)Tb + (size_t)(strip*16 + fr)*464;
        const char* brow = (const char*)Zb + (size_t)fr*448;
        #pragma unroll
        for (int kt = 0; kt < 7; ++kt) {
            short8v a  = *(const short8v*)(arow + kt*64 + g*16);
            short8v bb = *(const short8v*)(brow + kt*64 + g*16);
            acc = __builtin_amdgcn_mfma_f32_16x16x32_bf16(a, bb, acc, 0, 0, 0);
        }
        #pragma unroll
        for (int reg = 0; reg < 4; ++reg) {
            int prow = strip*16 + g*4 + reg;
            Pb[prow*16 + fr] = f2b(acc[reg]);
        }
    }
    __syncthreads();
    // ---- 8) T = (Lk - P U^T)/alpha (MFMA, K=16 zero-padded), diag -> dv ----
    for (int tile = wv_; tile < 169; tile += 16) {
        int R = tile / 13, Cc = tile - R*13;
        const short8v* pa = (g < 2) ? (const short8v*)((char*)Pb + (R*16 + fr)*32 + g*16) : zpad;
        const short8v* pb = (g < 2) ? (const short8v*)((char*)Ub + (Cc*16 + fr)*32 + g*16) : zpad;
        f32x4 acc = {0.f, 0.f, 0.f, 0.f};
        acc = __builtin_amdgcn_mfma_f32_16x16x32_bf16(*pa, *pb, acc, 0, 0, 0);
        #pragma unroll
        for (int reg = 0; reg < 4; ++reg) {
            int row = R*16 + g*4 + reg, col = Cc*16 + fr;
            if (row < LL && col < LL) {
                float lk = b2f(Tb[row*232 + col]);
                float tv = (lk - acc[reg]) * INV_ALPHA;
                if (row == col) dv[row] = tv;
                Tb[row*232 + col] = f2b(tv);
            }
        }
    }
    __syncthreads();
    // ---- 9) W = T .* T^T in place (symmetric) + denom ----
    {
        float wvp[20];
        float sTT = 0.f;
        #pragma unroll
        for (int it = 0; it < 20; ++it) {
            int i = t + it*1024;
            if (i < 20100) {
                int l, m;
                if (i < 20000) { l = i % 200; m = l + i/200; if (m >= 200) m -= 200; }
                else { l = i - 20000; m = l + 100; }
                float a = b2f(Tb[l*232 + m]);
                float c = b2f(Tb[m*232 + l]);
                float p = a*c;
                wvp[it] = p;
                sTT += (l == m) ? p : 2.0f*p;
            }
        }
        __syncthreads();   // all reads done before symmetric writes
        #pragma unroll
        for (int it = 0; it < 20; ++it) {
            int i = t + it*1024;
            if (i < 20100) {
                int l, m;
                if (i < 20000) { l = i % 200; m = l + i/200; if (m >= 200) m -= 200; }
                else { l = i - 20000; m = l + 100; }
                unsigned short h = f2b(wvp[it]);
                Tb[l*232 + m] = h;
                Tb[m*232 + l] = h;
            }
        }
        float sd = (t < LL) ? dv[t] : 0.f;
        for (int off = 32; off > 0; off >>= 1) {
            sTT += __shfl_xor(sTT, off);
            sd  += __shfl_xor(sd,  off);
        }
        if (lane == 0) { red[wv_] = sTT; red[16 + wv_] = sd; }
        __syncthreads();
        if (t == 0) {
            float s1 = 0.f, s2 = 0.f;
            for (int k = 0; k < 16; ++k) { s1 += red[k]; s2 += red[16 + k]; }
            float dn = fmaxf(0.5f*(s2*s2 - s1), 1e-9f);
            scal[0] = 1.0f / dn;
        }
        __syncthreads();
    }
    // ---- 10) per-wave strips (no intervening barrier):
    //      4-row-parallel softmax (one row per 16-lane group, 13 elems/lane,
    //      4-step shuffle reductions, full-strip mask prefetched to regs)
    //      -> attn(in Tb) -> PV -> proj -> LN ----
    {
        const unsigned short* Vt = Abuf;
        float invden = scal[0];
        float bdv[4], gv[4], bev[4];
        #pragma unroll
        for (int d2 = 0; d2 < 4; ++d2) {
            bdv[d2] = bd[d2*16 + fr];
            gv[d2]  = gamma[d2*16 + fr];
            bev[d2] = beta[d2*16 + fr];
        }
        char* hb = smem + OFF_UB + wv_*1152;   // u16[16][36] per wave
        // one softmax row, executed by this lane's 16-lane group (group row l)
        auto dorow = [&](const float (&mk)[13], int l) {
            if (l < LL) {                       // uniform within 16-lane group
                float dl = dv[l];
                float sc[13]; float mx = -3e38f;
                #pragma unroll
                for (int e = 0; e < 13; ++e) {
                    int m = fr + 16*e;
                    if (m < LL) {
                        float wlm = b2f(Tb[l*232 + m]);
                        float sub = fmaf(dl, dv[m], -wlm);
                        float s = -(sub*invden + ((m == l) ? dl : 0.f))*INV_SQRT_HEAD
                                  + mk[e];
                        sc[e] = s; mx = fmaxf(mx, s);
                    } else sc[e] = -3e38f;
                }
                mx = fmaxf(mx, __shfl_xor(mx, 1));
                mx = fmaxf(mx, __shfl_xor(mx, 2));
                mx = fmaxf(mx, __shfl_xor(mx, 4));
                mx = fmaxf(mx, __shfl_xor(mx, 8));
                float sum = 0.f;
                #pragma unroll
                for (int e = 0; e < 13; ++e) {
                    int m = fr + 16*e;
                    float ev = (m < LL) ? __expf(sc[e] - mx) : 0.f;
                    sc[e] = ev; sum += ev;
                }
                sum += __shfl_xor(sum, 1);
                sum += __shfl_xor(sum, 2);
                sum += __shfl_xor(sum, 4);
                sum += __shfl_xor(sum, 8);
                float isum = 1.0f / sum;
                #pragma unroll
                for (int e = 0; e < 13; ++e) {
                    int m = fr + 16*e;
                    if (m < LL) Tb[l*232 + m] = f2b(sc[e]*isum);
                }
            }
        };
        for (int sp = wv_; sp < 13; sp += 16) {
            // prefetch ALL mask values for this strip (52 floats/lane):
            // latency fully amortized before the softmax chains start
            float mka0[13], mka1[13], mka2[13], mka3[13];
            {
                const float* mrow = mask + (size_t)b*40000 + (size_t)(sp*16 + g)*200;
                int l8 = sp*16 + g + 8;    // rows +8/+12 exceed LL only at sp=12
                #pragma unroll
                for (int e = 0; e < 13; ++e) {
                    int m = fr + 16*e;
                    bool mm = (m < LL);
                    mka0[e] = mm                  ? mrow[m]        : 0.f;
                    mka1[e] = mm                  ? mrow[800 + m]  : 0.f;
                    mka2[e] = (mm && l8 < LL)     ? mrow[1600 + m] : 0.f;
                    mka3[e] = (mm && l8 + 4 < LL) ? mrow[2400 + m] : 0.f;
                }
            }
            dorow(mka0, sp*16 + g);
            dorow(mka1, sp*16 + 4 + g);
            dorow(mka2, sp*16 + 8 + g);
            dorow(mka3, sp*16 + 12 + g);
            // PV: ctx(16x64) = attn(16x224) @ Vt^T
            f32x4 cacc[4];
            #pragma unroll
            for (int d2 = 0; d2 < 4; ++d2) { f32x4 z = {0.f,0.f,0.f,0.f}; cacc[d2] = z; }
            {
                const char* arow = (const char*)Tb + (size_t)(sp*16 + fr)*464;
                #pragma unroll
                for (int kt = 0; kt < 7; ++kt) {
                    short8v a = *(const short8v*)(arow + kt*64 + g*16);
                    #pragma unroll
                    for (int d2 = 0; d2 < 4; ++d2) {
                        short8v bb = *(const short8v*)((const char*)Vt + (d2*16 + fr)*464 + kt*64 + g*16);
                        cacc[d2] = __builtin_amdgcn_mfma_f32_16x16x32_bf16(a, bb, cacc[d2], 0, 0, 0);
                    }
                }
            }
            // out-proj via halfbuf: two K=32 halves
            f32x4 oacc[4];
            #pragma unroll
            for (int d2 = 0; d2 < 4; ++d2) { f32x4 z = {0.f,0.f,0.f,0.f}; oacc[d2] = z; }
            #pragma unroll
            for (int h = 0; h < 2; ++h) {
                #pragma unroll
                for (int d2 = 0; d2 < 2; ++d2)
                    #pragma unroll
                    for (int reg = 0; reg < 4; ++reg)
                        *(unsigned short*)(hb + ((g*4 + reg)*36 + d2*16 + fr)*2) = f2b(cacc[h*2 + d2][reg]);
                short8v a = *(const short8v*)(hb + fr*72 + g*16);
                #pragma unroll
                for (int d2 = 0; d2 < 4; ++d2) {
                    short8v bb = *(const short8v*)((const char*)Wdb + (d2*16 + fr)*144 + h*64 + g*16);
                    oacc[d2] = __builtin_amdgcn_mfma_f32_16x16x32_bf16(a, bb, oacc[d2], 0, 0, 0);
                }
            }
            // LN over 64 dims (16-lane-group shuffles) + residual + store
            #pragma unroll
            for (int reg = 0; reg < 4; ++reg) {
                int l = sp*16 + g*4 + reg;
                if (l < LL) {
                    size_t xo = ((size_t)b*LL + l)*64 + fr;
                    float z0 = oacc[0][reg] + bdv[0] + x[xo];
                    float z1 = oacc[1][reg] + bdv[1] + x[xo + 16];
                    float z2 = oacc[2][reg] + bdv[2] + x[xo + 32];
                    float z3 = oacc[3][reg] + bdv[3] + x[xo + 48];
                    float s = z0 + z1 + z2 + z3;
                    s += __shfl_xor(s, 1); s += __shfl_xor(s, 2);
                    s += __shfl_xor(s, 4); s += __shfl_xor(s, 8);
                    float mu = s * (1.0f/64.0f);
                    float c0 = z0 - mu, c1 = z1 - mu, c2 = z2 - mu, c3 = z3 - mu;
                    float vs = c0*c0 + c1*c1 + c2*c2 + c3*c3;
                    vs += __shfl_xor(vs, 1); vs += __shfl_xor(vs, 2);
                    vs += __shfl_xor(vs, 4); vs += __shfl_xor(vs, 8);
                    float rstd = rsqrtf(vs * (1.0f/64.0f) + 1e-12f);
                    float* op = out + ((size_t)b*LL + l)*64 + fr;
                    op[0]  = fmaf(gv[0]*rstd, c0, bev[0]);
                    op[16] = fmaf(gv[1]*rstd, c1, bev[1]);
                    op[32] = fmaf(gv[2]*rstd, c2, bev[2]);
                    op[48] = fmaf(gv[3]*rstd, c3, bev[3]);
                }
            }
        }
    }
}

// ---------------------------------------------------------------------------
extern "C" void kernel_launch(void* const* d_in, const int* in_sizes, int n_in,
                              void* d_out, int out_size, void* d_ws, size_t ws_size,
                              hipStream_t stream) {
    const float* x     = (const float*)d_in[0];
    const float* mask  = (const float*)d_in[1];
    const int*   ids   = (const int*)  d_in[2];
    const float* C     = (const float*)d_in[3];
    const float* Wq    = (const float*)d_in[4];
    const float* bq    = (const float*)d_in[5];
    const float* Wv    = (const float*)d_in[6];
    const float* bv    = (const float*)d_in[7];
    const float* Wd    = (const float*)d_in[8];
    const float* bd    = (const float*)d_in[9];
    const float* gamma = (const float*)d_in[10];
    const float* beta  = (const float*)d_in[11];
    float* out = (float*)d_out;

    unsigned short* Vb = (unsigned short*)d_ws;   // 6,553,600 B

    mega_kernel<<<NB, 1024, LDS_TOTAL, stream>>>(x, mask, ids, C, Wq, bq, Wv, bv,
                                                 Wd, bd, gamma, beta, Vb, out);
}

// Round 2
// 78.028 us; speedup vs baseline: 1.1238x; 1.0240x over previous
//
#include <hip/hip_runtime.h>
#include <hip/hip_bf16.h>
#include <math.h>

// Problem constants
#define NB 256
#define LL 200
#define DD 64
#define ITEMS_N 10000
#define RANK 16
#define ALPHA 1.0001f
#define INV_ALPHA (1.0f/1.0001f)
#define INV_SQRT_HEAD 0.17677669529663687f  // 1/sqrt(32)

typedef __attribute__((ext_vector_type(8))) short short8v;
typedef __attribute__((ext_vector_type(4))) float f32x4;

static __device__ __forceinline__ unsigned short f2b(float f) {
    unsigned u = __float_as_uint(f);
    unsigned r = (u + 0x7fffu + ((u >> 16) & 1u)) >> 16;   // RNE
    return (unsigned short)r;
}
static __device__ __forceinline__ float b2f(unsigned short h) {
    return __uint_as_float(((unsigned)h) << 16);
}

// LDS layout (bytes) for mega
#define OFF_A     0        // Abuf u16[208][72] : S2 (MFMA output), later Vt u16[64][232]
#define OFF_TB    29952    // Tb u16[208][232]
// scratch aliased in the head of Tb:
#define OFF_CL32  (OFF_TB + 0)       // f32[32][33] candidate Gram (4224 B), dead after 1b
#define OFF_U32   (OFF_TB + 4224)    // f32[32][17] selection chol (2176 B), dead after 1d
#define OFF_UTL   (OFF_TB + 6400)    // u16[16][224] U^T lo-part (7168 B, ends 13568),
                                     //   written 1d, read ph.3 MFMA, dead before R=0/1 tiles (4+5)
#define OFF_XB    (OFF_TB + 20000)   // u16[208][72] x bf16          (29952 B, ends 49952)
#define OFF_WQB   (OFF_TB + 49952)   // u16[64][72]  Wq bf16         ( 9216 B, ends 59168)
#define OFF_WVB   (OFF_TB + 59168)   // u16[64][72]  Wv bf16         ( 9216 B, ends 68384)
#define OFF_BQS   (OFF_TB + 68384)   // f32[64]
#define OFF_BVS   (OFF_TB + 68640)   // f32[64]  (scratch ends 68896 < 96512)
#define OFF_UL    126464   // Ul f32[200][16] -> later Wdb u16[64][72]
#define OFF_UB    139264   // Ub u16[208][16] (written 1d); phase 10: per-wave halfbuf
                           //   u16[16][36] x 16 = 18,432 B (139264..157696 < dv at 159744)
#define OFF_PB    145920   // Pb u16[208][16] (written ph.7); before that hosts scratch:
#define OFF_MAUG  (OFF_PB + 0)       // f32[16][33] 2112 B (ph.3-5)
#define OFF_IDSL  (OFF_PB + 2112)    // int[200] (ph.0-1d)
#define OFF_PIV   (OFF_PB + 2912)    // int[16]
#define OFF_INVSQ (OFF_PB + 2976)    // f32[16]
#define OFF_IDP   (OFF_PB + 3040)    // int[16] (ends 3104 < 6656)
#define OFF_ZB    152576   // Zb u16[16][224]; 1d->ph.3 hosts U^T hi-part (alias), Z from 4+5
#define OFF_UTH   OFF_ZB
#define OFF_DV    159744   // dv f32[208]
#define OFF_RED   160576   // red f32[32]
#define OFF_SCAL  160704   // scal f32[4]
#define OFF_ZPAD  160720   // 64 B zeros
#define LDS_TOTAL 160784

// ---------------------------------------------------------------------------
// K_mega (single kernel). This round:
//  - 1c gather fused into 1d (per-thread register gather, -1 barrier, no Clg)
//  - phase 2 replaced by wave-0 split-bf16 MFMA (M = hh+hl+lh, f32-accurate)
//    merged with GJ in phase 3 (-1 barrier); tiles R<2 + pad rows 0-29 move to 4+5
//  - phases 8+9 fused via tile pairing + in-wave shfl transpose (-2 barriers,
//    removes the 20k-element W read-modify-write pass; W/denom from f32 T)
// grid B, block 1024 (16 waves), dynamic LDS 160,784 B (1 block/CU).
// ---------------------------------------------------------------------------
__global__ __launch_bounds__(1024) void mega_kernel(
        const float* __restrict__ x,    const float* __restrict__ mask,
        const int*   __restrict__ ids,  const float* __restrict__ C,
        const float* __restrict__ Wq,   const float* __restrict__ bq,
        const float* __restrict__ Wv,   const float* __restrict__ bv,
        const float* __restrict__ Wd,   const float* __restrict__ bd,
        const float* __restrict__ gamma,const float* __restrict__ beta,
        unsigned short* __restrict__ Vg, float* __restrict__ out) {
    extern __shared__ char smem[];
    unsigned short* Abuf = (unsigned short*)(smem + OFF_A);   // S2 then Vt
    unsigned short* Tb   = (unsigned short*)(smem + OFF_TB);
    float* Cl32  = (float*)(smem + OFF_CL32);
    float* U32l  = (float*)(smem + OFF_U32);
    unsigned short* xbu  = (unsigned short*)(smem + OFF_XB);
    unsigned short* Wqbu = (unsigned short*)(smem + OFF_WQB);
    unsigned short* Wvbu = (unsigned short*)(smem + OFF_WVB);
    float* bqs   = (float*)(smem + OFF_BQS);
    float* bvs   = (float*)(smem + OFF_BVS);
    float*          Ul   = (float*)(smem + OFF_UL);
    unsigned short* Wdb  = (unsigned short*)(smem + OFF_UL);  // alias (Ul dead)
    unsigned short* Ub   = (unsigned short*)(smem + OFF_UB);
    unsigned short* Pb   = (unsigned short*)(smem + OFF_PB);
    unsigned short* Zb   = (unsigned short*)(smem + OFF_ZB);
    float* dv   = (float*)(smem + OFF_DV);
    float* red  = (float*)(smem + OFF_RED);
    float* scal = (float*)(smem + OFF_SCAL);
    const short8v* zpad = (const short8v*)(smem + OFF_ZPAD);
    int*   idsl  = (int*)(smem + OFF_IDSL);
    int*   pivots= (int*)(smem + OFF_PIV);
    float* invsqv= (float*)(smem + OFF_INVSQ);
    int*   idpv  = (int*)(smem + OFF_IDP);
    float* Maug  = (float*)(smem + OFF_MAUG);

    int t = threadIdx.x;
    int b = blockIdx.x;
    int wv_ = t >> 6, lane = t & 63, fr = lane & 15, g = lane >> 4;

    // ---- -1) early Gram-gather issue (hides scattered-HBM latency under 0) ----
    int ga_ = t >> 5, gc_ = t & 31;
    float cgv;
    {
        int ia = ids[b*LL + ga_];
        int ic = ids[b*LL + gc_];
        cgv = C[(size_t)ia*ITEMS_N + ic];
    }

    // ---- 0) stage ids, x->bf16, Wq/Wv->bf16, biases; zero pads ----
    {
        float4 z4; z4.x = 0.f; z4.y = 0.f; z4.z = 0.f; z4.w = 0.f;
        // Tb rows 200-207 (3,712 B)
        float4* tz = (float4*)(smem + OFF_TB + 92800);
        for (int i = t; i < 232; i += 1024) tz[i] = z4;
        // Zb (also zero-pads U^T hi cols 200-223 for ph.3 MFMA)
        float4* zz = (float4*)Zb;
        for (int i = t; i < 448; i += 1024) zz[i] = z4;
        if (t < 4) ((float4*)(smem + OFF_ZPAD))[t] = z4;
        if (t < 64)  ((unsigned*)(smem + OFF_UB + 6400))[t] = 0;   // Ub rows 200-207
        // xb pad rows 200-207 (1,152 B)
        for (int i = t; i < 288; i += 1024) ((unsigned*)(smem + OFF_XB + 28800))[i] = 0;
        // x -> bf16 (float4-vectorized)
        const float4* x4p = (const float4*)(x + (size_t)b*12800);
        #pragma unroll
        for (int it2 = 0; it2 < 4; ++it2) {
            int i4 = t + it2*1024;
            if (i4 < 3200) {
                float4 v4 = x4p[i4];
                int r = i4 >> 4, k4 = (i4 & 15) << 2;
                unsigned lo = (unsigned)f2b(v4.x) | ((unsigned)f2b(v4.y) << 16);
                unsigned hi = (unsigned)f2b(v4.z) | ((unsigned)f2b(v4.w) << 16);
                *(uint2*)(xbu + r*72 + k4) = make_uint2(lo, hi);
            }
        }
        // Wq/Wv -> bf16
        {
            float4 q4 = ((const float4*)Wq)[t];
            float4 w4 = ((const float4*)Wv)[t];
            int d2 = t >> 4, k4 = (t & 15) << 2;
            unsigned qlo = (unsigned)f2b(q4.x) | ((unsigned)f2b(q4.y) << 16);
            unsigned qhi = (unsigned)f2b(q4.z) | ((unsigned)f2b(q4.w) << 16);
            *(uint2*)(Wqbu + d2*72 + k4) = make_uint2(qlo, qhi);
            unsigned vlo = (unsigned)f2b(w4.x) | ((unsigned)f2b(w4.y) << 16);
            unsigned vhi = (unsigned)f2b(w4.z) | ((unsigned)f2b(w4.w) << 16);
            *(uint2*)(Wvbu + d2*72 + k4) = make_uint2(vlo, vhi);
        }
        if (t < 64) { bqs[t] = bq[t]; bvs[t] = bv[t]; }
        if (t < LL) idsl[t] = ids[b*LL + t];
        Cl32[ga_*33 + gc_] = cgv;     // gather landed during staging
    }
    __syncthreads();

    // ---- 0.5) S2/V MFMA ----
    for (int tile = wv_; tile < 52; tile += 16) {
        int R = tile >> 2, Dt = tile & 3;
        const char* ar = (const char*)smem + OFF_XB + (R*16 + fr)*144;
        const char* qr = (const char*)smem + OFF_WQB + (Dt*16 + fr)*144;
        const char* vr = (const char*)smem + OFF_WVB + (Dt*16 + fr)*144;
        short8v a0 = *(const short8v*)(ar + g*16);
        short8v a1 = *(const short8v*)(ar + 64 + g*16);
        f32x4 qa = {0.f,0.f,0.f,0.f};
        f32x4 va = {0.f,0.f,0.f,0.f};
        qa = __builtin_amdgcn_mfma_f32_16x16x32_bf16(a0, *(const short8v*)(qr + g*16), qa, 0,0,0);
        qa = __builtin_amdgcn_mfma_f32_16x16x32_bf16(a1, *(const short8v*)(qr + 64 + g*16), qa, 0,0,0);
        va = __builtin_amdgcn_mfma_f32_16x16x32_bf16(a0, *(const short8v*)(vr + g*16), va, 0,0,0);
        va = __builtin_amdgcn_mfma_f32_16x16x32_bf16(a1, *(const short8v*)(vr + 64 + g*16), va, 0,0,0);
        int col = Dt*16 + fr;
        float bqc = bqs[col], bvc = bvs[col];
        #pragma unroll
        for (int reg = 0; reg < 4; ++reg) {
            int row = R*16 + g*4 + reg;
            float sv = qa[reg] + bqc;
            Abuf[row*72 + col] = (row < LL) ? f2b(sv*sv) : (unsigned short)0;
            if (row < LL) Vg[(size_t)b*12800 + row*64 + col] = f2b(va[reg] + bvc);
        }
    }
    __syncthreads();

    // ---- 1b) wave 0: selection Cholesky; waves 1-15: 130 Lk tiles R>=3
    //      (rows >=48, byte >=22272 — above all live Tb-head scratch). ----
    if (wv_ == 0) {
        int a = lane & 31;
        float diag = Cl32[a*33 + a] - 1.0f;
        float ur[16];
        int   mypiv = 0; float myinv = 0.f;
        bool  removed = false;
        #pragma unroll
        for (int s = 0; s < RANK; ++s) {
            float v = removed ? -3e38f : diag;
            int idx = a;
            #pragma unroll
            for (int off = 16; off > 0; off >>= 1) {
                float v2 = __shfl_xor(v, off);
                int   i2 = __shfl_xor(idx, off);
                if (v2 > v || (v2 == v && i2 < idx)) { v = v2; idx = i2; }
            }
            int p = idx; float dp = v;          // wave-uniform (p < 32)
            float iv = (dp < 1e-9f) ? 0.0f : (1.0f/sqrtf(dp));
            float c = Cl32[a*33 + p] - ((a == p) ? 1.0f : 0.0f);
            #pragma unroll
            for (int k = 0; k < s; ++k) {
                float upk = __shfl(ur[k], p);   // pivot row value U32[p][k]
                c -= ur[k] * upk;
            }
            float u = c * iv;
            ur[s] = u;
            diag -= u*u;
            if (a == p) removed = true;
            if (lane == s) { mypiv = p; myinv = iv; }
        }
        #pragma unroll
        for (int s = 0; s < RANK; ++s) U32l[a*17 + s] = ur[s];
        if (lane < 16) {
            pivots[lane] = mypiv;
            invsqv[lane] = myinv;
            idpv[lane]   = idsl[mypiv];
        }
    } else {
        for (int tile = 39 + (wv_ - 1); tile < 169; tile += 15) {
            int R = tile / 13, Cc = tile - R*13;
            short8v a0 = *(const short8v*)((char*)Abuf + (R*16 + fr)*144 + g*16);
            short8v a1 = *(const short8v*)((char*)Abuf + (R*16 + fr)*144 + 64 + g*16);
            short8v b0 = *(const short8v*)((char*)Abuf + (Cc*16 + fr)*144 + g*16);
            short8v b1 = *(const short8v*)((char*)Abuf + (Cc*16 + fr)*144 + 64 + g*16);
            f32x4 acc = {0.f, 0.f, 0.f, 0.f};
            acc = __builtin_amdgcn_mfma_f32_16x16x32_bf16(a0, b0, acc, 0, 0, 0);
            acc = __builtin_amdgcn_mfma_f32_16x16x32_bf16(a1, b1, acc, 0, 0, 0);
            int col = Cc*16 + fr;
            #pragma unroll
            for (int reg = 0; reg < 4; ++reg) {
                int row = R*16 + g*4 + reg;
                if (row < LL && col < LL) Tb[row*232 + col] = f2b(acc[reg]);
            }
        }
    }
    __syncthreads();

    // ---- 1d) fused gather+recursion: thread t<200 gathers its own 16 pivot
    //      values to registers, recurses, writes Ul(f32), Ub(bf16) and the
    //      split U^T (hi in Zb, lo in Tb head) for the ph.3 M-MFMA. ----
    if (t < LL) {
        int myrow = idsl[t];
        float cg[16];
        #pragma unroll
        for (int s = 0; s < RANK; ++s)
            cg[s] = C[(size_t)myrow*ITEMS_N + idpv[s]];
        float ur[16];
        #pragma unroll
        for (int s = 0; s < RANK; ++s) {
            int p = pivots[s];
            float c = cg[s] - ((t == p) ? 1.0f : 0.0f);
            #pragma unroll
            for (int k = 0; k < s; ++k) c -= ur[k] * U32l[p*17 + k];
            ur[s] = c * invsqv[s];
        }
        unsigned short* Uth = (unsigned short*)(smem + OFF_UTH);
        unsigned short* Utl = (unsigned short*)(smem + OFF_UTL);
        #pragma unroll
        for (int s = 0; s < RANK; ++s) {
            float v = ur[s];
            Ul[t*RANK + s] = v;
            unsigned short hv = f2b(v);
            Ub[t*RANK + s] = hv;
            Uth[s*224 + t] = hv;
            Utl[s*224 + t] = f2b(v - b2f(hv));
        }
    } else if (t < 392) {
        // zero U^T-lo pad cols 200-223 (hi pad already zero via Zb zeroing)
        int i = t - 200;            // 0..191
        int s = i / 12, c2 = i - s*12;
        *(unsigned*)(smem + OFF_UTL + s*448 + 400 + c2*4) = 0;
    }
    __syncthreads();

    // ---- Vt async prefetch (T14: Vg complete since 0.5; lands during 3-5) ----
    unsigned short vreg[13];
    {
        const unsigned short* vgp = Vg + (size_t)b*12800;
        #pragma unroll
        for (int it2 = 0; it2 < 13; ++it2) {
            int i = t + it2*1024;
            vreg[it2] = (i < 12800) ? vgp[i] : (unsigned short)0;
        }
    }

    // ---- 3) wave 0: M = alpha I + U^T U via split-bf16 MFMA (hh+hl+lh,
    //      f32-equivalent), then Gauss-Jordan (same wave, no barrier).
    //      waves 1-15: pad-zero rows 30-199 + the 13 tiles R=2. ----
    if (wv_ == 0) {
        const char* uh  = smem + OFF_UTH;
        const char* ul2 = smem + OFF_UTL;
        f32x4 macc = {0.f,0.f,0.f,0.f};
        #pragma unroll
        for (int kb = 0; kb < 7; ++kb) {
            short8v h  = *(const short8v*)(uh  + fr*448 + kb*64 + g*16);
            short8v l2 = *(const short8v*)(ul2 + fr*448 + kb*64 + g*16);
            macc = __builtin_amdgcn_mfma_f32_16x16x32_bf16(h,  h,  macc, 0,0,0);
            macc = __builtin_amdgcn_mfma_f32_16x16x32_bf16(h,  l2, macc, 0,0,0);
            macc = __builtin_amdgcn_mfma_f32_16x16x32_bf16(l2, h,  macc, 0,0,0);
        }
        #pragma unroll
        for (int reg = 0; reg < 4; ++reg) {
            int r = g*4 + reg;
            Maug[r*33 + fr]      = macc[reg] + ((r == fr) ? ALPHA : 0.f);
            Maug[r*33 + 16 + fr] = (r == fr) ? 1.0f : 0.0f;
        }
        // Gauss-Jordan (wave-internal LDS ordering via waitcnt)
        for (int s = 0; s < 16; ++s) {
            float pvinv = 1.0f / Maug[s*33 + s];
            float rowv = 0.f;
            if (lane < 33) { rowv = Maug[s*33 + lane] * pvinv; Maug[s*33 + lane] = rowv; }
            for (int r = 0; r < 16; ++r) {
                if (r == s) continue;
                float f = Maug[r*33 + s];
                if (lane < 33) Maug[r*33 + lane] -= f * rowv;
            }
        }
    } else {
        // Tb pad cols 200-231, rows 30-199 (safe above U^T-lo which ends 13568)
        for (int i = t - 64; i < 2720; i += 960) {
            int r = 30 + (i >> 4), c2 = i & 15;
            *(unsigned*)(smem + OFF_TB + r*464 + 400 + c2*4) = 0;
        }
        int tl = wv_ - 1;
        if (tl < 13) {
            int R = 2, Cc = tl;
            short8v a0 = *(const short8v*)((char*)Abuf + (R*16 + fr)*144 + g*16);
            short8v a1 = *(const short8v*)((char*)Abuf + (R*16 + fr)*144 + 64 + g*16);
            short8v b0 = *(const short8v*)((char*)Abuf + (Cc*16 + fr)*144 + g*16);
            short8v b1 = *(const short8v*)((char*)Abuf + (Cc*16 + fr)*144 + 64 + g*16);
            f32x4 acc = {0.f, 0.f, 0.f, 0.f};
            acc = __builtin_amdgcn_mfma_f32_16x16x32_bf16(a0, b0, acc, 0, 0, 0);
            acc = __builtin_amdgcn_mfma_f32_16x16x32_bf16(a1, b1, acc, 0, 0, 0);
            int col = Cc*16 + fr;
            #pragma unroll
            for (int reg = 0; reg < 4; ++reg) {
                int row = R*16 + g*4 + reg;
                if (row < LL && col < LL) Tb[row*232 + col] = f2b(acc[reg]);
            }
        }
    }
    __syncthreads();

    // ---- 4+5) Z = U*Minv -> Zb (overwrites dead U^T-hi); tiles R=0,1
    //      (rows 0-31, over dead Cl32/U32/U^T-lo); pad rows 0-29. ----
    for (int idx = t; idx < LL*RANK; idx += 1024) {
        int i = idx >> 4, r = idx & 15;
        float acc = 0.f;
        #pragma unroll
        for (int k = 0; k < 16; ++k) acc = fmaf(Ul[i*RANK + k], Maug[k*33 + 16 + r], acc);
        Zb[r*224 + i] = f2b(acc);
    }
    if (t < 480) {
        int r = t >> 4, c2 = t & 15;
        *(unsigned*)(smem + OFF_TB + r*464 + 400 + c2*4) = 0;
    }
    for (int u2 = wv_; u2 < 26; u2 += 16) {
        int R = u2 / 13, Cc = u2 - R*13;
        short8v a0 = *(const short8v*)((char*)Abuf + (R*16 + fr)*144 + g*16);
        short8v a1 = *(const short8v*)((char*)Abuf + (R*16 + fr)*144 + 64 + g*16);
        short8v b0 = *(const short8v*)((char*)Abuf + (Cc*16 + fr)*144 + g*16);
        short8v b1 = *(const short8v*)((char*)Abuf + (Cc*16 + fr)*144 + 64 + g*16);
        f32x4 acc = {0.f, 0.f, 0.f, 0.f};
        acc = __builtin_amdgcn_mfma_f32_16x16x32_bf16(a0, b0, acc, 0, 0, 0);
        acc = __builtin_amdgcn_mfma_f32_16x16x32_bf16(a1, b1, acc, 0, 0, 0);
        int col = Cc*16 + fr;
        #pragma unroll
        for (int reg = 0; reg < 4; ++reg) {
            int row = R*16 + g*4 + reg;
            if (row < LL && col < LL) Tb[row*232 + col] = f2b(acc[reg]);
        }
    }
    __syncthreads();            // Maug read done; Tb holds full Lk + zero pads

    // ---- 7) Vt stage (from vreg; S2 dead) + Wdb stage (Ul dead after this
    //      phase's P... Ul only read in 4+5 — Wdb aliases Ul, safe now) +
    //      P = Lk@Z MFMA -> Pb ----
    {
        unsigned short* Vt = Abuf;
        #pragma unroll
        for (int it2 = 0; it2 < 13; ++it2) {
            int i = t + it2*1024;
            if (i < 12800) Vt[(i & 63)*232 + (i >> 6)] = vreg[it2];
        }
        for (int i = t; i < 2048; i += 1024) {
            int d = i >> 5, mc = i & 31;
            Vt[d*232 + 200 + mc] = 0;
        }
        for (int i = t; i < 4096; i += 1024) {
            int dd = i >> 6, k = i & 63;
            Wdb[dd*72 + k] = f2b(Wd[i]);
        }
    }
    for (int strip = wv_; strip < 13; strip += 16) {
        f32x4 acc = {0.f, 0.f, 0.f, 0.f};
        const char* arow = (const char*)Tb + (size_t)(strip*16 + fr)*464;
        const char* brow = (const char*)Zb + (size_t)fr*448;
        #pragma unroll
        for (int kt = 0; kt < 7; ++kt) {
            short8v a  = *(const short8v*)(arow + kt*64 + g*16);
            short8v bb = *(const short8v*)(brow + kt*64 + g*16);
            acc = __builtin_amdgcn_mfma_f32_16x16x32_bf16(a, bb, acc, 0, 0, 0);
        }
        #pragma unroll
        for (int reg = 0; reg < 4; ++reg) {
            int prow = strip*16 + g*4 + reg;
            Pb[prow*16 + fr] = f2b(acc[reg]);
        }
    }
    __syncthreads();

    // ---- 8+9 fused: per tile-pair compute T (f32, via MFMA), transpose
    //      in-wave via shfl, W = T.*T^T written once, dv + sTT/diag partial
    //      sums inline. No cross-wave T reads -> no intermediate barrier. ----
    {
        float ps = 0.f, psd = 0.f;
        for (int u = wv_; u < 91; u += 16) {
            int R, Cc;
            if (u < 13) { R = u; Cc = u; }
            else {
                int q = u - 13, rr = 0;
                while (q >= 12 - rr) { q -= 12 - rr; ++rr; }
                R = rr; Cc = rr + 1 + q;
            }
            const short8v* paA = (g < 2) ? (const short8v*)((const char*)Pb + (R*16 + fr)*32 + g*16) : zpad;
            const short8v* pbA = (g < 2) ? (const short8v*)((const char*)Ub + (Cc*16 + fr)*32 + g*16) : zpad;
            f32x4 accA = {0.f,0.f,0.f,0.f};
            accA = __builtin_amdgcn_mfma_f32_16x16x32_bf16(*paA, *pbA, accA, 0,0,0);
            float tvA[4];
            #pragma unroll
            for (int reg = 0; reg < 4; ++reg) {
                int row = R*16 + g*4 + reg, col = Cc*16 + fr;
                float lk = b2f(Tb[row*232 + col]);   // rows/cols >=200 read 0
                tvA[reg] = (lk - accA[reg]) * INV_ALPHA;
            }
            if (u < 13) {
                float tAt[4];
                #pragma unroll
                for (int reg = 0; reg < 4; ++reg) {
                    int sl = (fr >> 2)*16 + g*4 + reg;
                    float z0 = __shfl(tvA[0], sl), z1 = __shfl(tvA[1], sl),
                          z2 = __shfl(tvA[2], sl), z3 = __shfl(tvA[3], sl);
                    int k2 = fr & 3;
                    tAt[reg] = (k2 == 0) ? z0 : (k2 == 1) ? z1 : (k2 == 2) ? z2 : z3;
                }
                #pragma unroll
                for (int reg = 0; reg < 4; ++reg) {
                    int row = R*16 + g*4 + reg, col = R*16 + fr;
                    if (row < LL && col < LL) {
                        float w = tvA[reg] * tAt[reg];
                        Tb[row*232 + col] = f2b(w);
                        ps += w;
                        if (row == col) { dv[row] = tvA[reg]; psd += tvA[reg]; }
                    }
                }
            } else {
                const short8v* paB = (g < 2) ? (const short8v*)((const char*)Pb + (Cc*16 + fr)*32 + g*16) : zpad;
                const short8v* pbB = (g < 2) ? (const short8v*)((const char*)Ub + (R*16 + fr)*32 + g*16) : zpad;
                f32x4 accB = {0.f,0.f,0.f,0.f};
                accB = __builtin_amdgcn_mfma_f32_16x16x32_bf16(*paB, *pbB, accB, 0,0,0);
                float tvB[4];
                #pragma unroll
                for (int reg = 0; reg < 4; ++reg) {
                    int row = Cc*16 + g*4 + reg, col = R*16 + fr;
                    float lk = b2f(Tb[row*232 + col]);
                    tvB[reg] = (lk - accB[reg]) * INV_ALPHA;
                }
                float tAt[4], tBt[4];
                #pragma unroll
                for (int reg = 0; reg < 4; ++reg) {
                    int sl = (fr >> 2)*16 + g*4 + reg;
                    float a0 = __shfl(tvA[0], sl), a1 = __shfl(tvA[1], sl),
                          a2 = __shfl(tvA[2], sl), a3 = __shfl(tvA[3], sl);
                    float b0 = __shfl(tvB[0], sl), b1 = __shfl(tvB[1], sl),
                          b2 = __shfl(tvB[2], sl), b3 = __shfl(tvB[3], sl);
                    int k2 = fr & 3;
                    tAt[reg] = (k2 == 0) ? a0 : (k2 == 1) ? a1 : (k2 == 2) ? a2 : a3;
                    tBt[reg] = (k2 == 0) ? b0 : (k2 == 1) ? b1 : (k2 == 2) ? b2 : b3;
                }
                #pragma unroll
                for (int reg = 0; reg < 4; ++reg) {
                    int rowA = R*16 + g*4 + reg, colA = Cc*16 + fr;
                    if (rowA < LL && colA < LL) {
                        float wA = tvA[reg] * tBt[reg];
                        Tb[rowA*232 + colA] = f2b(wA);
                        ps += 2.0f * wA;
                    }
                    int rowB = Cc*16 + g*4 + reg, colB = R*16 + fr;
                    if (rowB < LL && colB < LL) {
                        float wB = tvB[reg] * tAt[reg];
                        Tb[rowB*232 + colB] = f2b(wB);
                    }
                }
            }
        }
        #pragma unroll
        for (int off = 32; off > 0; off >>= 1) {
            ps  += __shfl_xor(ps, off);
            psd += __shfl_xor(psd, off);
        }
        if (lane == 0) { red[wv_] = ps; red[16 + wv_] = psd; }
        __syncthreads();
        if (t == 0) {
            float s1 = 0.f, s2 = 0.f;
            for (int k = 0; k < 16; ++k) { s1 += red[k]; s2 += red[16 + k]; }
            float dn = fmaxf(0.5f*(s2*s2 - s1), 1e-9f);
            scal[0] = 1.0f / dn;
        }
        __syncthreads();
    }

    // ---- 10) per-wave strips: 4-row-parallel softmax -> PV -> proj -> LN ----
    {
        const unsigned short* Vt = Abuf;
        float invden = scal[0];
        float bdv[4], gv[4], bev[4];
        #pragma unroll
        for (int d2 = 0; d2 < 4; ++d2) {
            bdv[d2] = bd[d2*16 + fr];
            gv[d2]  = gamma[d2*16 + fr];
            bev[d2] = beta[d2*16 + fr];
        }
        char* hb = smem + OFF_UB + wv_*1152;   // u16[16][36] per wave
        auto dorow = [&](const float (&mk)[13], int l) {
            if (l < LL) {                       // uniform within 16-lane group
                float dl = dv[l];
                float sc[13]; float mx = -3e38f;
                #pragma unroll
                for (int e = 0; e < 13; ++e) {
                    int m = fr + 16*e;
                    if (m < LL) {
                        float wlm = b2f(Tb[l*232 + m]);
                        float sub = fmaf(dl, dv[m], -wlm);
                        float s = -(sub*invden + ((m == l) ? dl : 0.f))*INV_SQRT_HEAD
                                  + mk[e];
                        sc[e] = s; mx = fmaxf(mx, s);
                    } else sc[e] = -3e38f;
                }
                mx = fmaxf(mx, __shfl_xor(mx, 1));
                mx = fmaxf(mx, __shfl_xor(mx, 2));
                mx = fmaxf(mx, __shfl_xor(mx, 4));
                mx = fmaxf(mx, __shfl_xor(mx, 8));
                float sum = 0.f;
                #pragma unroll
                for (int e = 0; e < 13; ++e) {
                    int m = fr + 16*e;
                    float ev = (m < LL) ? __expf(sc[e] - mx) : 0.f;
                    sc[e] = ev; sum += ev;
                }
                sum += __shfl_xor(sum, 1);
                sum += __shfl_xor(sum, 2);
                sum += __shfl_xor(sum, 4);
                sum += __shfl_xor(sum, 8);
                float isum = 1.0f / sum;
                #pragma unroll
                for (int e = 0; e < 13; ++e) {
                    int m = fr + 16*e;
                    if (m < LL) Tb[l*232 + m] = f2b(sc[e]*isum);
                }
            }
        };
        for (int sp = wv_; sp < 13; sp += 16) {
            float mka0[13], mka1[13], mka2[13], mka3[13];
            {
                const float* mrow = mask + (size_t)b*40000 + (size_t)(sp*16 + g)*200;
                int l8 = sp*16 + g + 8;
                #pragma unroll
                for (int e = 0; e < 13; ++e) {
                    int m = fr + 16*e;
                    bool mm = (m < LL);
                    mka0[e] = mm                  ? mrow[m]        : 0.f;
                    mka1[e] = mm                  ? mrow[800 + m]  : 0.f;
                    mka2[e] = (mm && l8 < LL)     ? mrow[1600 + m] : 0.f;
                    mka3[e] = (mm && l8 + 4 < LL) ? mrow[2400 + m] : 0.f;
                }
            }
            dorow(mka0, sp*16 + g);
            dorow(mka1, sp*16 + 4 + g);
            dorow(mka2, sp*16 + 8 + g);
            dorow(mka3, sp*16 + 12 + g);
            // PV: ctx(16x64) = attn(16x224) @ Vt^T
            f32x4 cacc[4];
            #pragma unroll
            for (int d2 = 0; d2 < 4; ++d2) { f32x4 z = {0.f,0.f,0.f,0.f}; cacc[d2] = z; }
            {
                const char* arow = (const char*)Tb + (size_t)(sp*16 + fr)*464;
                #pragma unroll
                for (int kt = 0; kt < 7; ++kt) {
                    short8v a = *(const short8v*)(arow + kt*64 + g*16);
                    #pragma unroll
                    for (int d2 = 0; d2 < 4; ++d2) {
                        short8v bb = *(const short8v*)((const char*)Vt + (d2*16 + fr)*464 + kt*64 + g*16);
                        cacc[d2] = __builtin_amdgcn_mfma_f32_16x16x32_bf16(a, bb, cacc[d2], 0, 0, 0);
                    }
                }
            }
            // out-proj via halfbuf: two K=32 halves
            f32x4 oacc[4];
            #pragma unroll
            for (int d2 = 0; d2 < 4; ++d2) { f32x4 z = {0.f,0.f,0.f,0.f}; oacc[d2] = z; }
            #pragma unroll
            for (int h = 0; h < 2; ++h) {
                #pragma unroll
                for (int d2 = 0; d2 < 2; ++d2)
                    #pragma unroll
                    for (int reg = 0; reg < 4; ++reg)
                        *(unsigned short*)(hb + ((g*4 + reg)*36 + d2*16 + fr)*2) = f2b(cacc[h*2 + d2][reg]);
                short8v a = *(const short8v*)(hb + fr*72 + g*16);
                #pragma unroll
                for (int d2 = 0; d2 < 4; ++d2) {
                    short8v bb = *(const short8v*)((const char*)Wdb + (d2*16 + fr)*144 + h*64 + g*16);
                    oacc[d2] = __builtin_amdgcn_mfma_f32_16x16x32_bf16(a, bb, oacc[d2], 0, 0, 0);
                }
            }
            // LN over 64 dims + residual + store
            #pragma unroll
            for (int reg = 0; reg < 4; ++reg) {
                int l = sp*16 + g*4 + reg;
                if (l < LL) {
                    size_t xo = ((size_t)b*LL + l)*64 + fr;
                    float z0 = oacc[0][reg] + bdv[0] + x[xo];
                    float z1 = oacc[1][reg] + bdv[1] + x[xo + 16];
                    float z2 = oacc[2][reg] + bdv[2] + x[xo + 32];
                    float z3 = oacc[3][reg] + bdv[3] + x[xo + 48];
                    float s = z0 + z1 + z2 + z3;
                    s += __shfl_xor(s, 1); s += __shfl_xor(s, 2);
                    s += __shfl_xor(s, 4); s += __shfl_xor(s, 8);
                    float mu = s * (1.0f/64.0f);
                    float c0 = z0 - mu, c1 = z1 - mu, c2 = z2 - mu, c3 = z3 - mu;
                    float vs = c0*c0 + c1*c1 + c2*c2 + c3*c3;
                    vs += __shfl_xor(vs, 1); vs += __shfl_xor(vs, 2);
                    vs += __shfl_xor(vs, 4); vs += __shfl_xor(vs, 8);
                    float rstd = rsqrtf(vs * (1.0f/64.0f) + 1e-12f);
                    float* op = out + ((size_t)b*LL + l)*64 + fr;
                    op[0]  = fmaf(gv[0]*rstd, c0, bev[0]);
                    op[16] = fmaf(gv[1]*rstd, c1, bev[1]);
                    op[32] = fmaf(gv[2]*rstd, c2, bev[2]);
                    op[48] = fmaf(gv[3]*rstd, c3, bev[3]);
                }
            }
        }
    }
}

// ---------------------------------------------------------------------------
extern "C" void kernel_launch(void* const* d_in, const int* in_sizes, int n_in,
                              void* d_out, int out_size, void* d_ws, size_t ws_size,
                              hipStream_t stream) {
    const float* x     = (const float*)d_in[0];
    const float* mask  = (const float*)d_in[1];
    const int*   ids   = (const int*)  d_in[2];
    const float* C     = (const float*)d_in[3];
    const float* Wq    = (const float*)d_in[4];
    const float* bq    = (const float*)d_in[5];
    const float* Wv    = (const float*)d_in[6];
    const float* bv    = (const float*)d_in[7];
    const float* Wd    = (const float*)d_in[8];
    const float* bd    = (const float*)d_in[9];
    const float* gamma = (const float*)d_in[10];
    const float* beta  = (const float*)d_in[11];
    float* out = (float*)d_out;

    unsigned short* Vb = (unsigned short*)d_ws;   // 6,553,600 B

    mega_kernel<<<NB, 1024, LDS_TOTAL, stream>>>(x, mask, ids, C, Wq, bq, Wv, bv,
                                                 Wd, bd, gamma, beta, Vb, out);
}

// Round 3
// 69.516 us; speedup vs baseline: 1.2614x; 1.1225x over previous
//
#include <hip/hip_runtime.h>
#include <hip/hip_bf16.h>
#include <math.h>

// Problem constants
#define NB 256
#define LL 200
#define DD 64
#define ITEMS_N 10000
#define RANK 16
#define ALPHA 1.0001f
#define INV_ALPHA (1.0f/1.0001f)
#define INV_SQRT_HEAD 0.17677669529663687f  // 1/sqrt(32)

typedef __attribute__((ext_vector_type(8))) short short8v;
typedef __attribute__((ext_vector_type(4))) float f32x4;

static __device__ __forceinline__ unsigned short f2b(float f) {
    unsigned u = __float_as_uint(f);
    unsigned r = (u + 0x7fffu + ((u >> 16) & 1u)) >> 16;   // RNE
    return (unsigned short)r;
}
static __device__ __forceinline__ float b2f(unsigned short h) {
    return __uint_as_float(((unsigned)h) << 16);
}

// LDS layout (bytes) for mega
#define OFF_A     0        // Abuf u16[208][72] : S2 (MFMA output), later Vt u16[64][232]
#define OFF_TB    29952    // Tb u16[208][232]
// scratch aliased in the head of Tb:
#define OFF_CL32  (OFF_TB + 0)       // f32[32][33] candidate Gram (4224 B), dead after 1b
#define OFF_U32   (OFF_TB + 4224)    // f32[32][17] selection chol (2176 B), dead after 1d
#define OFF_UTL   (OFF_TB + 6400)    // u16[16][224] U^T lo-part (7168 B, ends 13568),
                                     //   written 1d, read ph.3 MFMA, dead before R=0/1 tiles (4+5)
#define OFF_XB    (OFF_TB + 20000)   // u16[208][72] x bf16          (29952 B, ends 49952)
#define OFF_WQB   (OFF_TB + 49952)   // u16[64][72]  Wq bf16         ( 9216 B, ends 59168)
#define OFF_WVB   (OFF_TB + 59168)   // u16[64][72]  Wv bf16         ( 9216 B, ends 68384)
#define OFF_BQS   (OFF_TB + 68384)   // f32[64]
#define OFF_BVS   (OFF_TB + 68640)   // f32[64]  (scratch ends 68896 < 96512)
#define OFF_UL    126464   // Ul f32[200][16] -> later Wdb u16[64][72]
#define OFF_UB    139264   // Ub u16[208][16] (written 1d); phase 10: per-wave halfbuf
                           //   u16[16][36] x 16 = 18,432 B (139264..157696 < dv at 159744)
#define OFF_PB    145920   // Pb u16[208][16] (written ph.7); before that hosts scratch:
#define OFF_MAUG  (OFF_PB + 0)       // f32[16][33] 2112 B (ph.3-5)
#define OFF_IDSL  (OFF_PB + 2112)    // int[200] (ph.0-1d)
#define OFF_PIV   (OFF_PB + 2912)    // int[16]
#define OFF_INVSQ (OFF_PB + 2976)    // f32[16]
#define OFF_IDP   (OFF_PB + 3040)    // int[16] (ends 3104 < 6656)
#define OFF_ZB    152576   // Zb u16[16][224]; 1d->ph.3 hosts U^T hi-part (alias), Z from 4+5
#define OFF_UTH   OFF_ZB
#define OFF_DV    159744   // dv f32[208]
#define OFF_RED   160576   // red f32[32]
#define OFF_SCAL  160704   // scal f32[4]
#define OFF_ZPAD  160720   // 64 B zeros
#define LDS_TOTAL 160784

// ---------------------------------------------------------------------------
// K_mega. This round:
//  - V held in packed VGPRs 0.5 -> 7 (no Vg global round-trip, -13 MB HBM)
//  - Lk tile rebalance: 45 tiles in 1b, 65 in 1d (waves 4-15, hides C gather),
//    33 in ph.3 (hides GJ), 26 (R=0,1) in 4+5
//  - register Gauss-Jordan on wave 0 (row-per-lane, shfl; ~3x faster)
//  - 8+9: symmetric-Lk double-MFMA (T and T^T tiles both via MFMA, no shuffles)
//  - phase 10: x prefetched into regs after softmax (hidden under PV MFMA)
// grid B, block 1024 (16 waves), dynamic LDS 160,784 B (1 block/CU).
// ---------------------------------------------------------------------------
__global__ __launch_bounds__(1024) void mega_kernel(
        const float* __restrict__ x,    const float* __restrict__ mask,
        const int*   __restrict__ ids,  const float* __restrict__ C,
        const float* __restrict__ Wq,   const float* __restrict__ bq,
        const float* __restrict__ Wv,   const float* __restrict__ bv,
        const float* __restrict__ Wd,   const float* __restrict__ bd,
        const float* __restrict__ gamma,const float* __restrict__ beta,
        unsigned short* __restrict__ Vg, float* __restrict__ out) {
    extern __shared__ char smem[];
    unsigned short* Abuf = (unsigned short*)(smem + OFF_A);   // S2 then Vt
    unsigned short* Tb   = (unsigned short*)(smem + OFF_TB);
    float* Cl32  = (float*)(smem + OFF_CL32);
    float* U32l  = (float*)(smem + OFF_U32);
    unsigned short* xbu  = (unsigned short*)(smem + OFF_XB);
    unsigned short* Wqbu = (unsigned short*)(smem + OFF_WQB);
    unsigned short* Wvbu = (unsigned short*)(smem + OFF_WVB);
    float* bqs   = (float*)(smem + OFF_BQS);
    float* bvs   = (float*)(smem + OFF_BVS);
    float*          Ul   = (float*)(smem + OFF_UL);
    unsigned short* Wdb  = (unsigned short*)(smem + OFF_UL);  // alias (Ul dead)
    unsigned short* Ub   = (unsigned short*)(smem + OFF_UB);
    unsigned short* Pb   = (unsigned short*)(smem + OFF_PB);
    unsigned short* Zb   = (unsigned short*)(smem + OFF_ZB);
    float* dv   = (float*)(smem + OFF_DV);
    float* red  = (float*)(smem + OFF_RED);
    float* scal = (float*)(smem + OFF_SCAL);
    const short8v* zpad = (const short8v*)(smem + OFF_ZPAD);
    int*   idsl  = (int*)(smem + OFF_IDSL);
    int*   pivots= (int*)(smem + OFF_PIV);
    float* invsqv= (float*)(smem + OFF_INVSQ);
    int*   idpv  = (int*)(smem + OFF_IDP);
    float* Maug  = (float*)(smem + OFF_MAUG);

    int t = threadIdx.x;
    int b = blockIdx.x;
    int wv_ = t >> 6, lane = t & 63, fr = lane & 15, g = lane >> 4;

    // ---- -1) early Gram-gather issue (hides scattered-HBM latency under 0) ----
    int ga_ = t >> 5, gc_ = t & 31;
    float cgv;
    {
        int ia = ids[b*LL + ga_];
        int ic = ids[b*LL + gc_];
        cgv = C[(size_t)ia*ITEMS_N + ic];
    }

    // ---- 0) stage ids, x->bf16, Wq/Wv->bf16, biases; zero pads ----
    {
        float4 z4; z4.x = 0.f; z4.y = 0.f; z4.z = 0.f; z4.w = 0.f;
        // Tb rows 200-207 (3,712 B)
        float4* tz = (float4*)(smem + OFF_TB + 92800);
        for (int i = t; i < 232; i += 1024) tz[i] = z4;
        // Zb (also zero-pads U^T hi cols 200-223 for ph.3 MFMA)
        float4* zz = (float4*)Zb;
        for (int i = t; i < 448; i += 1024) zz[i] = z4;
        if (t < 4) ((float4*)(smem + OFF_ZPAD))[t] = z4;
        if (t < 64)  ((unsigned*)(smem + OFF_UB + 6400))[t] = 0;   // Ub rows 200-207
        // U^T-lo pad cols 200-223 (192 words; region untouched until 1d writes)
        if (t < 192) {
            int s = t / 12, c2 = t - s*12;
            *(unsigned*)(smem + OFF_UTL + s*448 + 400 + c2*4) = 0;
        }
        // xb pad rows 200-207 (1,152 B)
        for (int i = t; i < 288; i += 1024) ((unsigned*)(smem + OFF_XB + 28800))[i] = 0;
        // x -> bf16 (float4-vectorized)
        const float4* x4p = (const float4*)(x + (size_t)b*12800);
        #pragma unroll
        for (int it2 = 0; it2 < 4; ++it2) {
            int i4 = t + it2*1024;
            if (i4 < 3200) {
                float4 v4 = x4p[i4];
                int r = i4 >> 4, k4 = (i4 & 15) << 2;
                unsigned lo = (unsigned)f2b(v4.x) | ((unsigned)f2b(v4.y) << 16);
                unsigned hi = (unsigned)f2b(v4.z) | ((unsigned)f2b(v4.w) << 16);
                *(uint2*)(xbu + r*72 + k4) = make_uint2(lo, hi);
            }
        }
        // Wq/Wv -> bf16
        {
            float4 q4 = ((const float4*)Wq)[t];
            float4 w4 = ((const float4*)Wv)[t];
            int d2 = t >> 4, k4 = (t & 15) << 2;
            unsigned qlo = (unsigned)f2b(q4.x) | ((unsigned)f2b(q4.y) << 16);
            unsigned qhi = (unsigned)f2b(q4.z) | ((unsigned)f2b(q4.w) << 16);
            *(uint2*)(Wqbu + d2*72 + k4) = make_uint2(qlo, qhi);
            unsigned vlo = (unsigned)f2b(w4.x) | ((unsigned)f2b(w4.y) << 16);
            unsigned vhi = (unsigned)f2b(w4.z) | ((unsigned)f2b(w4.w) << 16);
            *(uint2*)(Wvbu + d2*72 + k4) = make_uint2(vlo, vhi);
        }
        if (t < 64) { bqs[t] = bq[t]; bvs[t] = bv[t]; }
        if (t < LL) idsl[t] = ids[b*LL + t];
        Cl32[ga_*33 + gc_] = cgv;     // gather landed during staging
    }
    __syncthreads();

    // ---- 0.5) S2/V MFMA; V held in packed regs until phase 7 ----
    unsigned vpack[8];
    #pragma unroll
    for (int it2 = 0; it2 < 4; ++it2) {
        int tile = wv_ + 16*it2;
        vpack[2*it2] = 0; vpack[2*it2 + 1] = 0;
        if (tile < 52) {
            int R = tile >> 2, Dt = tile & 3;
            const char* ar = (const char*)smem + OFF_XB + (R*16 + fr)*144;
            const char* qr = (const char*)smem + OFF_WQB + (Dt*16 + fr)*144;
            const char* vr = (const char*)smem + OFF_WVB + (Dt*16 + fr)*144;
            short8v a0 = *(const short8v*)(ar + g*16);
            short8v a1 = *(const short8v*)(ar + 64 + g*16);
            f32x4 qa = {0.f,0.f,0.f,0.f};
            f32x4 va = {0.f,0.f,0.f,0.f};
            qa = __builtin_amdgcn_mfma_f32_16x16x32_bf16(a0, *(const short8v*)(qr + g*16), qa, 0,0,0);
            qa = __builtin_amdgcn_mfma_f32_16x16x32_bf16(a1, *(const short8v*)(qr + 64 + g*16), qa, 0,0,0);
            va = __builtin_amdgcn_mfma_f32_16x16x32_bf16(a0, *(const short8v*)(vr + g*16), va, 0,0,0);
            va = __builtin_amdgcn_mfma_f32_16x16x32_bf16(a1, *(const short8v*)(vr + 64 + g*16), va, 0,0,0);
            int col = Dt*16 + fr;
            float bqc = bqs[col], bvc = bvs[col];
            #pragma unroll
            for (int reg = 0; reg < 4; ++reg) {
                int row = R*16 + g*4 + reg;
                float sv = qa[reg] + bqc;
                Abuf[row*72 + col] = (row < LL) ? f2b(sv*sv) : (unsigned short)0;
            }
            vpack[2*it2]     = (unsigned)f2b(va[0] + bvc) | ((unsigned)f2b(va[1] + bvc) << 16);
            vpack[2*it2 + 1] = (unsigned)f2b(va[2] + bvc) | ((unsigned)f2b(va[3] + bvc) << 16);
        }
    }
    __syncthreads();

    // ---- 1b) wave 0: selection Cholesky; waves 1-15: 45 Lk tiles
    //      (R>=2 global idx 0..44; rows >=32, above live Cl32/U32l). ----
    if (wv_ == 0) {
        int a = lane & 31;
        float diag = Cl32[a*33 + a] - 1.0f;
        float ur[16];
        int   mypiv = 0; float myinv = 0.f;
        bool  removed = false;
        #pragma unroll
        for (int s = 0; s < RANK; ++s) {
            float v = removed ? -3e38f : diag;
            int idx = a;
            #pragma unroll
            for (int off = 16; off > 0; off >>= 1) {
                float v2 = __shfl_xor(v, off);
                int   i2 = __shfl_xor(idx, off);
                if (v2 > v || (v2 == v && i2 < idx)) { v = v2; idx = i2; }
            }
            int p = idx; float dp = v;          // wave-uniform (p < 32)
            float iv = (dp < 1e-9f) ? 0.0f : (1.0f/sqrtf(dp));
            float c = Cl32[a*33 + p] - ((a == p) ? 1.0f : 0.0f);
            #pragma unroll
            for (int k = 0; k < s; ++k) {
                float upk = __shfl(ur[k], p);   // pivot row value U32[p][k]
                c -= ur[k] * upk;
            }
            float u = c * iv;
            ur[s] = u;
            diag -= u*u;
            if (a == p) removed = true;
            if (lane == s) { mypiv = p; myinv = iv; }
        }
        #pragma unroll
        for (int s = 0; s < RANK; ++s) U32l[a*17 + s] = ur[s];
        if (lane < 16) {
            pivots[lane] = mypiv;
            invsqv[lane] = myinv;
            idpv[lane]   = idsl[mypiv];
        }
    } else {
        for (int idx = wv_ - 1; idx < 45; idx += 15) {
            int R = 2 + idx/13, Cc = idx % 13;
            short8v a0 = *(const short8v*)((char*)Abuf + (R*16 + fr)*144 + g*16);
            short8v a1 = *(const short8v*)((char*)Abuf + (R*16 + fr)*144 + 64 + g*16);
            short8v b0 = *(const short8v*)((char*)Abuf + (Cc*16 + fr)*144 + g*16);
            short8v b1 = *(const short8v*)((char*)Abuf + (Cc*16 + fr)*144 + 64 + g*16);
            f32x4 acc = {0.f, 0.f, 0.f, 0.f};
            acc = __builtin_amdgcn_mfma_f32_16x16x32_bf16(a0, b0, acc, 0, 0, 0);
            acc = __builtin_amdgcn_mfma_f32_16x16x32_bf16(a1, b1, acc, 0, 0, 0);
            int col = Cc*16 + fr;
            #pragma unroll
            for (int reg = 0; reg < 4; ++reg) {
                int row = R*16 + g*4 + reg;
                if (row < LL && col < LL) Tb[row*232 + col] = f2b(acc[reg]);
            }
        }
    }
    __syncthreads();

    // ---- 1d) waves 0-3: per-thread pivot-col gather + U recursion;
    //      waves 4-15: 65 Lk tiles (idx 45..109, rows 80-175 — hides the
    //      3200-line scattered C gather behind MFMA). ----
    if (wv_ < 4) {
        if (t < LL) {
            int myrow = idsl[t];
            float cg[16];
            #pragma unroll
            for (int s = 0; s < RANK; ++s)
                cg[s] = C[(size_t)myrow*ITEMS_N + idpv[s]];
            float ur[16];
            #pragma unroll
            for (int s = 0; s < RANK; ++s) {
                int p = pivots[s];
                float c = cg[s] - ((t == p) ? 1.0f : 0.0f);
                #pragma unroll
                for (int k = 0; k < s; ++k) c -= ur[k] * U32l[p*17 + k];
                ur[s] = c * invsqv[s];
            }
            unsigned short* Uth = (unsigned short*)(smem + OFF_UTH);
            unsigned short* Utl = (unsigned short*)(smem + OFF_UTL);
            #pragma unroll
            for (int s = 0; s < RANK; ++s) {
                float v = ur[s];
                Ul[t*RANK + s] = v;
                unsigned short hv = f2b(v);
                Ub[t*RANK + s] = hv;
                Uth[s*224 + t] = hv;
                Utl[s*224 + t] = f2b(v - b2f(hv));
            }
        }
    } else {
        for (int idx = 45 + (wv_ - 4); idx < 110; idx += 12) {
            int R = 2 + idx/13, Cc = idx % 13;
            short8v a0 = *(const short8v*)((char*)Abuf + (R*16 + fr)*144 + g*16);
            short8v a1 = *(const short8v*)((char*)Abuf + (R*16 + fr)*144 + 64 + g*16);
            short8v b0 = *(const short8v*)((char*)Abuf + (Cc*16 + fr)*144 + g*16);
            short8v b1 = *(const short8v*)((char*)Abuf + (Cc*16 + fr)*144 + 64 + g*16);
            f32x4 acc = {0.f, 0.f, 0.f, 0.f};
            acc = __builtin_amdgcn_mfma_f32_16x16x32_bf16(a0, b0, acc, 0, 0, 0);
            acc = __builtin_amdgcn_mfma_f32_16x16x32_bf16(a1, b1, acc, 0, 0, 0);
            int col = Cc*16 + fr;
            #pragma unroll
            for (int reg = 0; reg < 4; ++reg) {
                int row = R*16 + g*4 + reg;
                if (row < LL && col < LL) Tb[row*232 + col] = f2b(acc[reg]);
            }
        }
    }
    __syncthreads();

    // ---- 3) wave 0: M = alpha I + U^T U (split-bf16 MFMA, f32-equivalent)
    //      then REGISTER Gauss-Jordan (row-per-lane, shfl).
    //      waves 1-15: pad-zero rows 30-199 + 33 tiles (idx 110..142). ----
    if (wv_ == 0) {
        const char* uh  = smem + OFF_UTH;
        const char* ul2 = smem + OFF_UTL;
        f32x4 macc = {0.f,0.f,0.f,0.f};
        #pragma unroll
        for (int kb = 0; kb < 7; ++kb) {
            short8v h  = *(const short8v*)(uh  + fr*448 + kb*64 + g*16);
            short8v l2 = *(const short8v*)(ul2 + fr*448 + kb*64 + g*16);
            macc = __builtin_amdgcn_mfma_f32_16x16x32_bf16(h,  h,  macc, 0,0,0);
            macc = __builtin_amdgcn_mfma_f32_16x16x32_bf16(h,  l2, macc, 0,0,0);
            macc = __builtin_amdgcn_mfma_f32_16x16x32_bf16(l2, h,  macc, 0,0,0);
        }
        #pragma unroll
        for (int reg = 0; reg < 4; ++reg) {
            int r = g*4 + reg;
            Maug[r*33 + fr] = macc[reg] + ((r == fr) ? ALPHA : 0.f);
        }
        // row-per-lane readback (lane r<16 holds M row r + inv row r)
        float m_[16], inv_[16];
        int rl = lane & 15;
        #pragma unroll
        for (int c = 0; c < 16; ++c) {
            m_[c]   = Maug[rl*33 + c];
            inv_[c] = (rl == c) ? 1.0f : 0.0f;
        }
        #pragma unroll
        for (int s = 0; s < 16; ++s) {
            float pv = __shfl(m_[s], s);
            float pvinv = 1.0f / pv;
            float f = m_[s];
            #pragma unroll
            for (int c = 0; c < 16; ++c) {
                float prow = __shfl(m_[c], s) * pvinv;
                float pinv = __shfl(inv_[c], s) * pvinv;
                if (lane == s) { m_[c] = prow; inv_[c] = pinv; }
                else { m_[c] = fmaf(-f, prow, m_[c]); inv_[c] = fmaf(-f, pinv, inv_[c]); }
            }
        }
        if (lane < 16) {
            #pragma unroll
            for (int c = 0; c < 16; ++c) Maug[lane*33 + 16 + c] = inv_[c];
        }
    } else {
        // Tb pad cols 200-231, rows 30-199 (above U^T-lo which ends 13568)
        for (int i = t - 64; i < 2720; i += 960) {
            int r = 30 + (i >> 4), c2 = i & 15;
            *(unsigned*)(smem + OFF_TB + r*464 + 400 + c2*4) = 0;
        }
        for (int idx = 110 + (wv_ - 1); idx < 143; idx += 15) {
            int R = 2 + idx/13, Cc = idx % 13;
            short8v a0 = *(const short8v*)((char*)Abuf + (R*16 + fr)*144 + g*16);
            short8v a1 = *(const short8v*)((char*)Abuf + (R*16 + fr)*144 + 64 + g*16);
            short8v b0 = *(const short8v*)((char*)Abuf + (Cc*16 + fr)*144 + g*16);
            short8v b1 = *(const short8v*)((char*)Abuf + (Cc*16 + fr)*144 + 64 + g*16);
            f32x4 acc = {0.f, 0.f, 0.f, 0.f};
            acc = __builtin_amdgcn_mfma_f32_16x16x32_bf16(a0, b0, acc, 0, 0, 0);
            acc = __builtin_amdgcn_mfma_f32_16x16x32_bf16(a1, b1, acc, 0, 0, 0);
            int col = Cc*16 + fr;
            #pragma unroll
            for (int reg = 0; reg < 4; ++reg) {
                int row = R*16 + g*4 + reg;
                if (row < LL && col < LL) Tb[row*232 + col] = f2b(acc[reg]);
            }
        }
    }
    __syncthreads();

    // ---- 4+5) Z = U*Minv -> Zb (overwrites dead U^T-hi); tiles R=0,1
    //      (rows 0-31, over dead Cl32/U32/U^T-lo); pad rows 0-29. ----
    for (int idx = t; idx < LL*RANK; idx += 1024) {
        int i = idx >> 4, r = idx & 15;
        float acc = 0.f;
        #pragma unroll
        for (int k = 0; k < 16; ++k) acc = fmaf(Ul[i*RANK + k], Maug[k*33 + 16 + r], acc);
        Zb[r*224 + i] = f2b(acc);
    }
    if (t < 480) {
        int r = t >> 4, c2 = t & 15;
        *(unsigned*)(smem + OFF_TB + r*464 + 400 + c2*4) = 0;
    }
    for (int u2 = wv_; u2 < 26; u2 += 16) {
        int R = u2 / 13, Cc = u2 - R*13;
        short8v a0 = *(const short8v*)((char*)Abuf + (R*16 + fr)*144 + g*16);
        short8v a1 = *(const short8v*)((char*)Abuf + (R*16 + fr)*144 + 64 + g*16);
        short8v b0 = *(const short8v*)((char*)Abuf + (Cc*16 + fr)*144 + g*16);
        short8v b1 = *(const short8v*)((char*)Abuf + (Cc*16 + fr)*144 + 64 + g*16);
        f32x4 acc = {0.f, 0.f, 0.f, 0.f};
        acc = __builtin_amdgcn_mfma_f32_16x16x32_bf16(a0, b0, acc, 0, 0, 0);
        acc = __builtin_amdgcn_mfma_f32_16x16x32_bf16(a1, b1, acc, 0, 0, 0);
        int col = Cc*16 + fr;
        #pragma unroll
        for (int reg = 0; reg < 4; ++reg) {
            int row = R*16 + g*4 + reg;
            if (row < LL && col < LL) Tb[row*232 + col] = f2b(acc[reg]);
        }
    }
    __syncthreads();            // Maug read done; Tb holds full Lk + zero pads

    // ---- 7) Vt stage from held regs (S2 dead) + Wdb stage (Ul dead) +
    //         P = Lk@Z MFMA -> Pb ----
    {
        unsigned short* Vt = Abuf;
        #pragma unroll
        for (int it2 = 0; it2 < 4; ++it2) {
            int tile = wv_ + 16*it2;
            if (tile < 52) {
                int R = tile >> 2, Dt = tile & 3;
                #pragma unroll
                for (int reg = 0; reg < 4; ++reg) {
                    int row = R*16 + g*4 + reg;
                    if (row < LL) {
                        unsigned short hv = (unsigned short)
                            ((vpack[2*it2 + (reg >> 1)] >> ((reg & 1)*16)) & 0xffffu);
                        Vt[(Dt*16 + fr)*232 + row] = hv;
                    }
                }
            }
        }
        for (int i = t; i < 2048; i += 1024) {
            int d = i >> 5, mc = i & 31;
            Vt[d*232 + 200 + mc] = 0;
        }
        for (int i = t; i < 4096; i += 1024) {
            int dd = i >> 6, k = i & 63;
            Wdb[dd*72 + k] = f2b(Wd[i]);
        }
    }
    for (int strip = wv_; strip < 13; strip += 16) {
        f32x4 acc = {0.f, 0.f, 0.f, 0.f};
        const char* arow = (const char*)Tb + (size_t)(strip*16 + fr)*464;
        const char* brow = (const char*)Zb + (size_t)fr*448;
        #pragma unroll
        for (int kt = 0; kt < 7; ++kt) {
            short8v a  = *(const short8v*)(arow + kt*64 + g*16);
            short8v bb = *(const short8v*)(brow + kt*64 + g*16);
            acc = __builtin_amdgcn_mfma_f32_16x16x32_bf16(a, bb, acc, 0, 0, 0);
        }
        #pragma unroll
        for (int reg = 0; reg < 4; ++reg) {
            int prow = strip*16 + g*4 + reg;
            Pb[prow*16 + fr] = f2b(acc[reg]);
        }
    }
    __syncthreads();

    // ---- 8+9 fused, symmetric-Lk: per tile (R,Cc) compute BOTH T[row][col]
    //      (PU^T MFMA) and T[col][row] (UP^T MFMA, operands swapped; uses
    //      Lk[row][col]=Lk[col][row]). W = T.*T^T written to both triangles.
    //      No shuffles. dv + sTT/diag partials inline. ----
    {
        float ps = 0.f, psd = 0.f;
        for (int u = wv_; u < 91; u += 16) {
            int R, Cc;
            if (u < 13) { R = u; Cc = u; }
            else {
                int q = u - 13, rr = 0;
                while (q >= 12 - rr) { q -= 12 - rr; ++rr; }
                R = rr; Cc = rr + 1 + q;
            }
            const short8v* pPR = (g < 2) ? (const short8v*)((const char*)Pb + (R*16 + fr)*32 + g*16) : zpad;
            const short8v* pUC = (g < 2) ? (const short8v*)((const char*)Ub + (Cc*16 + fr)*32 + g*16) : zpad;
            const short8v* pUR = (g < 2) ? (const short8v*)((const char*)Ub + (R*16 + fr)*32 + g*16) : zpad;
            const short8v* pPC = (g < 2) ? (const short8v*)((const char*)Pb + (Cc*16 + fr)*32 + g*16) : zpad;
            f32x4 acc1 = {0.f,0.f,0.f,0.f};
            f32x4 acc2 = {0.f,0.f,0.f,0.f};
            acc1 = __builtin_amdgcn_mfma_f32_16x16x32_bf16(*pPR, *pUC, acc1, 0,0,0);  // (PU^T)[row][col]
            acc2 = __builtin_amdgcn_mfma_f32_16x16x32_bf16(*pUR, *pPC, acc2, 0,0,0);  // (PU^T)[col][row]
            #pragma unroll
            for (int reg = 0; reg < 4; ++reg) {
                int row = R*16 + g*4 + reg, col = Cc*16 + fr;
                float lk = b2f(Tb[row*232 + col]);     // Lk symmetric
                float tvA = (lk - acc1[reg]) * INV_ALPHA;   // T[row][col]
                float tvT = (lk - acc2[reg]) * INV_ALPHA;   // T[col][row]
                if (row < LL && col < LL) {
                    float w = tvA * tvT;
                    unsigned short h = f2b(w);
                    Tb[row*232 + col] = h;
                    if (u >= 13) {
                        Tb[col*232 + row] = h;         // W symmetric
                        ps += 2.0f * w;
                    } else {
                        ps += w;
                        if (row == col) { dv[row] = tvA; psd += tvA; }
                    }
                }
            }
        }
        #pragma unroll
        for (int off = 32; off > 0; off >>= 1) {
            ps  += __shfl_xor(ps, off);
            psd += __shfl_xor(psd, off);
        }
        if (lane == 0) { red[wv_] = ps; red[16 + wv_] = psd; }
        __syncthreads();
        if (t == 0) {
            float s1 = 0.f, s2 = 0.f;
            for (int k = 0; k < 16; ++k) { s1 += red[k]; s2 += red[16 + k]; }
            float dn = fmaxf(0.5f*(s2*s2 - s1), 1e-9f);
            scal[0] = 1.0f / dn;
        }
        __syncthreads();
    }

    // ---- 10) per-wave strips: 4-row-parallel softmax -> x prefetch ->
    //      PV -> proj -> LN ----
    {
        const unsigned short* Vt = Abuf;
        float invden = scal[0];
        float bdv[4], gv[4], bev[4];
        #pragma unroll
        for (int d2 = 0; d2 < 4; ++d2) {
            bdv[d2] = bd[d2*16 + fr];
            gv[d2]  = gamma[d2*16 + fr];
            bev[d2] = beta[d2*16 + fr];
        }
        char* hb = smem + OFF_UB + wv_*1152;   // u16[16][36] per wave
        auto dorow = [&](const float (&mk)[13], int l) {
            if (l < LL) {                       // uniform within 16-lane group
                float dl = dv[l];
                float sc[13]; float mx = -3e38f;
                #pragma unroll
                for (int e = 0; e < 13; ++e) {
                    int m = fr + 16*e;
                    if (m < LL) {
                        float wlm = b2f(Tb[l*232 + m]);
                        float sub = fmaf(dl, dv[m], -wlm);
                        float s = -(sub*invden + ((m == l) ? dl : 0.f))*INV_SQRT_HEAD
                                  + mk[e];
                        sc[e] = s; mx = fmaxf(mx, s);
                    } else sc[e] = -3e38f;
                }
                mx = fmaxf(mx, __shfl_xor(mx, 1));
                mx = fmaxf(mx, __shfl_xor(mx, 2));
                mx = fmaxf(mx, __shfl_xor(mx, 4));
                mx = fmaxf(mx, __shfl_xor(mx, 8));
                float sum = 0.f;
                #pragma unroll
                for (int e = 0; e < 13; ++e) {
                    int m = fr + 16*e;
                    float ev = (m < LL) ? __expf(sc[e] - mx) : 0.f;
                    sc[e] = ev; sum += ev;
                }
                sum += __shfl_xor(sum, 1);
                sum += __shfl_xor(sum, 2);
                sum += __shfl_xor(sum, 4);
                sum += __shfl_xor(sum, 8);
                float isum = 1.0f / sum;
                #pragma unroll
                for (int e = 0; e < 13; ++e) {
                    int m = fr + 16*e;
                    if (m < LL) Tb[l*232 + m] = f2b(sc[e]*isum);
                }
            }
        };
        for (int sp = wv_; sp < 13; sp += 16) {
            float mka0[13], mka1[13], mka2[13], mka3[13];
            {
                const float* mrow = mask + (size_t)b*40000 + (size_t)(sp*16 + g)*200;
                int l8 = sp*16 + g + 8;
                #pragma unroll
                for (int e = 0; e < 13; ++e) {
                    int m = fr + 16*e;
                    bool mm = (m < LL);
                    mka0[e] = mm                  ? mrow[m]        : 0.f;
                    mka1[e] = mm                  ? mrow[800 + m]  : 0.f;
                    mka2[e] = (mm && l8 < LL)     ? mrow[1600 + m] : 0.f;
                    mka3[e] = (mm && l8 + 4 < LL) ? mrow[2400 + m] : 0.f;
                }
            }
            dorow(mka0, sp*16 + g);
            dorow(mka1, sp*16 + 4 + g);
            dorow(mka2, sp*16 + 8 + g);
            dorow(mka3, sp*16 + 12 + g);
            // x prefetch for LN (issued here, hidden under PV MFMA)
            float xp[16];
            #pragma unroll
            for (int d2 = 0; d2 < 4; ++d2)
                #pragma unroll
                for (int reg = 0; reg < 4; ++reg) {
                    int l = sp*16 + g*4 + reg;
                    xp[d2*4 + reg] = (l < LL)
                        ? x[((size_t)b*LL + l)*64 + d2*16 + fr] : 0.f;
                }
            // PV: ctx(16x64) = attn(16x224) @ Vt^T
            f32x4 cacc[4];
            #pragma unroll
            for (int d2 = 0; d2 < 4; ++d2) { f32x4 z = {0.f,0.f,0.f,0.f}; cacc[d2] = z; }
            {
                const char* arow = (const char*)Tb + (size_t)(sp*16 + fr)*464;
                #pragma unroll
                for (int kt = 0; kt < 7; ++kt) {
                    short8v a = *(const short8v*)(arow + kt*64 + g*16);
                    #pragma unroll
                    for (int d2 = 0; d2 < 4; ++d2) {
                        short8v bb = *(const short8v*)((const char*)Vt + (d2*16 + fr)*464 + kt*64 + g*16);
                        cacc[d2] = __builtin_amdgcn_mfma_f32_16x16x32_bf16(a, bb, cacc[d2], 0, 0, 0);
                    }
                }
            }
            // out-proj via halfbuf: two K=32 halves
            f32x4 oacc[4];
            #pragma unroll
            for (int d2 = 0; d2 < 4; ++d2) { f32x4 z = {0.f,0.f,0.f,0.f}; oacc[d2] = z; }
            #pragma unroll
            for (int h = 0; h < 2; ++h) {
                #pragma unroll
                for (int d2 = 0; d2 < 2; ++d2)
                    #pragma unroll
                    for (int reg = 0; reg < 4; ++reg)
                        *(unsigned short*)(hb + ((g*4 + reg)*36 + d2*16 + fr)*2) = f2b(cacc[h*2 + d2][reg]);
                short8v a = *(const short8v*)(hb + fr*72 + g*16);
                #pragma unroll
                for (int d2 = 0; d2 < 4; ++d2) {
                    short8v bb = *(const short8v*)((const char*)Wdb + (d2*16 + fr)*144 + h*64 + g*16);
                    oacc[d2] = __builtin_amdgcn_mfma_f32_16x16x32_bf16(a, bb, oacc[d2], 0, 0, 0);
                }
            }
            // LN over 64 dims + residual + store
            #pragma unroll
            for (int reg = 0; reg < 4; ++reg) {
                int l = sp*16 + g*4 + reg;
                if (l < LL) {
                    float z0 = oacc[0][reg] + bdv[0] + xp[reg];
                    float z1 = oacc[1][reg] + bdv[1] + xp[4 + reg];
                    float z2 = oacc[2][reg] + bdv[2] + xp[8 + reg];
                    float z3 = oacc[3][reg] + bdv[3] + xp[12 + reg];
                    float s = z0 + z1 + z2 + z3;
                    s += __shfl_xor(s, 1); s += __shfl_xor(s, 2);
                    s += __shfl_xor(s, 4); s += __shfl_xor(s, 8);
                    float mu = s * (1.0f/64.0f);
                    float c0 = z0 - mu, c1 = z1 - mu, c2 = z2 - mu, c3 = z3 - mu;
                    float vs = c0*c0 + c1*c1 + c2*c2 + c3*c3;
                    vs += __shfl_xor(vs, 1); vs += __shfl_xor(vs, 2);
                    vs += __shfl_xor(vs, 4); vs += __shfl_xor(vs, 8);
                    float rstd = rsqrtf(vs * (1.0f/64.0f) + 1e-12f);
                    float* op = out + ((size_t)b*LL + l)*64 + fr;
                    op[0]  = fmaf(gv[0]*rstd, c0, bev[0]);
                    op[16] = fmaf(gv[1]*rstd, c1, bev[1]);
                    op[32] = fmaf(gv[2]*rstd, c2, bev[2]);
                    op[48] = fmaf(gv[3]*rstd, c3, bev[3]);
                }
            }
        }
    }
}

// ---------------------------------------------------------------------------
extern "C" void kernel_launch(void* const* d_in, const int* in_sizes, int n_in,
                              void* d_out, int out_size, void* d_ws, size_t ws_size,
                              hipStream_t stream) {
    const float* x     = (const float*)d_in[0];
    const float* mask  = (const float*)d_in[1];
    const int*   ids   = (const int*)  d_in[2];
    const float* C     = (const float*)d_in[3];
    const float* Wq    = (const float*)d_in[4];
    const float* bq    = (const float*)d_in[5];
    const float* Wv    = (const float*)d_in[6];
    const float* bv    = (const float*)d_in[7];
    const float* Wd    = (const float*)d_in[8];
    const float* bd    = (const float*)d_in[9];
    const float* gamma = (const float*)d_in[10];
    const float* beta  = (const float*)d_in[11];
    float* out = (float*)d_out;

    unsigned short* Vb = (unsigned short*)d_ws;   // workspace (unused this round)

    mega_kernel<<<NB, 1024, LDS_TOTAL, stream>>>(x, mask, ids, C, Wq, bq, Wv, bv,
                                                 Wd, bd, gamma, beta, Vb, out);
}